// Round 2
// baseline (1757.612 us; speedup 1.0000x reference)
//
#include <hip/hip_runtime.h>
#include <hip/hip_bf16.h>
#include <cstdint>
#include <cstddef>

using bf16 = __hip_bfloat16;
typedef __attribute__((ext_vector_type(8))) short short8;
typedef __attribute__((ext_vector_type(4))) float f32x4;

typedef __attribute__((address_space(1))) const void as1_void;
typedef __attribute__((address_space(3))) void as3_void;

__device__ __forceinline__ f32x4 mfma16x16x32(short8 a, short8 b, f32x4 c) {
  return __builtin_amdgcn_mfma_f32_16x16x32_bf16(a, b, c, 0, 0, 0);
}

__device__ __forceinline__ void gload_lds16(const void* g, void* l) {
  __builtin_amdgcn_global_load_lds((as1_void*)g, (as3_void*)l, 16, 0, 0);
}

// ---------------- problem constants ----------------
// B=8, H=W=64, C=768, NH=12, HD=64, WS=14 -> Hp=Wp=70, 5x5 windows, Bn=200
// N=196 tokens/window, padded rows NPR=208 (13x16), padded keys NPK=224 (7x32)
// GEMM M (windowed) = 200*196 = 39200, padded 39296; dense tokens = 32768

static constexpr int MROWS = 39200;
static constexpr int MPAD  = 39296;
static constexpr int TOK2  = 32768;
static constexpr int NPR   = 208;
static constexpr int NPK   = 224;

// ---------------- weight transpose+cast:  in f32 [K][N] -> out bf16 [N][K] ----
__global__ __launch_bounds__(256)
void transpose_cast(const float* __restrict__ in, bf16* __restrict__ out, int K, int N) {
  __shared__ float t[32][33];
  const int tx = threadIdx.x & 31, ty = threadIdx.x >> 5;
  const int bx = blockIdx.x, by = blockIdx.y;   // bx: N-tile, by: K-tile
  const int x = bx * 32 + tx;
  for (int r = ty; r < 32; r += 8)
    t[r][tx] = in[(size_t)(by * 32 + r) * N + x];
  __syncthreads();
  const int xo = by * 32 + tx;
  for (int r = ty; r < 32; r += 8)
    out[(size_t)(bx * 32 + r) * K + xo] = __float2bfloat16(t[tx][r]);
}

// ---------------- LN1 + window partition -> bf16 [MPAD][768] ----------------
__global__ __launch_bounds__(256)
void ln1_partition(const float* __restrict__ x, const float* __restrict__ g,
                   const float* __restrict__ bb, bf16* __restrict__ out) {
  const int token = blockIdx.x * 4 + (threadIdx.x >> 6);  // < 39200
  const int lane = threadIdx.x & 63;
  const int win = token / 196, tok = token % 196;
  const int b_ = win / 25, wh = (win / 5) % 5, ww = win % 5;
  const int i = tok / 14, j = tok % 14;
  const int h = wh * 14 + i, w = ww * 14 + j;
  bf16* o = out + (size_t)token * 768;
  if (h >= 64 || w >= 64) {
    for (int t = 0; t < 12; ++t) o[lane + 64 * t] = __float2bfloat16(0.f);
    return;
  }
  const float* src = x + ((size_t)((b_ * 64 + h) * 64 + w)) * 768;
  float vals[12], s = 0.f, ss = 0.f;
  #pragma unroll
  for (int t = 0; t < 12; ++t) {
    float v = src[lane + 64 * t];
    vals[t] = v; s += v; ss += v * v;
  }
  #pragma unroll
  for (int d = 32; d > 0; d >>= 1) { s += __shfl_xor(s, d); ss += __shfl_xor(ss, d); }
  const float mu = s * (1.f / 768.f);
  const float var = ss * (1.f / 768.f) - mu * mu;
  const float inv = rsqrtf(var + 1e-6f);
  #pragma unroll
  for (int t = 0; t < 12; ++t) {
    const int c = lane + 64 * t;
    o[c] = __float2bfloat16((vals[t] - mu) * inv * g[c] + bb[c]);
  }
}

// ---------------- LN2 on x1 (f32, dense [32768][768]) -> bf16 ----------------
__global__ __launch_bounds__(256)
void ln2_kernel(const float* __restrict__ x1, const float* __restrict__ g,
                const float* __restrict__ bb, bf16* __restrict__ out) {
  const int token = blockIdx.x * 4 + (threadIdx.x >> 6);  // < 32768
  const int lane = threadIdx.x & 63;
  const float* src = x1 + (size_t)token * 768;
  bf16* o = out + (size_t)token * 768;
  float vals[12], s = 0.f, ss = 0.f;
  #pragma unroll
  for (int t = 0; t < 12; ++t) {
    float v = src[lane + 64 * t];
    vals[t] = v; s += v; ss += v * v;
  }
  #pragma unroll
  for (int d = 32; d > 0; d >>= 1) { s += __shfl_xor(s, d); ss += __shfl_xor(ss, d); }
  const float mu = s * (1.f / 768.f);
  const float var = ss * (1.f / 768.f) - mu * mu;
  const float inv = rsqrtf(var + 1e-6f);
  #pragma unroll
  for (int t = 0; t < 12; ++t) {
    const int c = lane + 64 * t;
    o[c] = __float2bfloat16((vals[t] - mu) * inv * g[c] + bb[c]);
  }
}

// ---------------- generic bf16 GEMM, 128x128 tile, BK=32, fused epilogues ----
// EPI 0: qkv scatter  (ob0/ob1/ob2 = q/k/v bufs [2400][208][64] bf16)
// EPI 1: proj -> unpartition + residual:  fout[idx] = fin[idx] + v   (f32)
// EPI 2: exact gelu -> ob0 bf16 [M][3072]
// EPI 3: fout[idx] = fin[idx] + v  (dense [M][768], f32)
template<int EPI>
__global__ __launch_bounds__(256)
void gemm_bf16(const bf16* __restrict__ A, const bf16* __restrict__ Bt,
               const float* __restrict__ bias, int K, int Mreal,
               const float* __restrict__ fin, float* __restrict__ fout,
               bf16* __restrict__ ob0, bf16* __restrict__ ob1, bf16* __restrict__ ob2) {
  __shared__ __align__(16) bf16 lA[128 * 32];
  __shared__ __align__(16) bf16 lB[128 * 32];
  const int tid = threadIdx.x;
  const int lane = tid & 63, wv = tid >> 6;
  const int lr = lane & 15, hi = lane >> 4;
  const int wm = wv >> 1, wn = wv & 1;
  const size_t arow0 = (size_t)blockIdx.y * 128;
  const size_t brow0 = (size_t)blockIdx.x * 128;
  f32x4 acc[4][4] = {};
  for (int k0 = 0; k0 < K; k0 += 32) {
    #pragma unroll
    for (int it = 0; it < 2; ++it) {
      const int seg = it * 256 + tid;
      const int row = seg >> 2, kq = seg & 3;
      gload_lds16(A + (arow0 + row) * K + k0 + kq * 8, &lA[(size_t)(it * 256 + wv * 64) * 8]);
      gload_lds16(Bt + (brow0 + row) * K + k0 + kq * 8, &lB[(size_t)(it * 256 + wv * 64) * 8]);
    }
    __syncthreads();
    short8 af[4], bfr[4];
    #pragma unroll
    for (int m = 0; m < 4; ++m) af[m] = *(const short8*)&lA[(wm * 64 + m * 16 + lr) * 32 + hi * 8];
    #pragma unroll
    for (int n = 0; n < 4; ++n) bfr[n] = *(const short8*)&lB[(wn * 64 + n * 16 + lr) * 32 + hi * 8];
    #pragma unroll
    for (int m = 0; m < 4; ++m)
      #pragma unroll
      for (int n = 0; n < 4; ++n)
        acc[m][n] = mfma16x16x32(af[m], bfr[n], acc[m][n]);
    __syncthreads();
  }
  // epilogue
  #pragma unroll
  for (int n = 0; n < 4; ++n) {
    const int col = (int)brow0 + wn * 64 + n * 16 + lr;
    const float bv = bias[col];
    #pragma unroll
    for (int m = 0; m < 4; ++m) {
      #pragma unroll
      for (int e = 0; e < 4; ++e) {
        const int row = (int)arow0 + wm * 64 + m * 16 + hi * 4 + e;
        const float v = acc[m][n][e] + bv;
        if constexpr (EPI == 0) {
          if (row < Mreal) {
            const int win = row / 196, tok = row % 196;
            const int which = col / 768, head = (col >> 6) % 12, d = col & 63;
            bf16* dst = (which == 0) ? ob0 : ((which == 1) ? ob1 : ob2);
            dst[((size_t)(win * 12 + head) * NPR + tok) * 64 + d] = __float2bfloat16(v);
          }
        } else if constexpr (EPI == 1) {
          if (row < Mreal) {
            const int win = row / 196, tok = row % 196;
            const int b_ = win / 25, wh = (win / 5) % 5, ww = win % 5;
            const int i = tok / 14, j = tok % 14;
            const int h = wh * 14 + i, w = ww * 14 + j;
            if (h < 64 && w < 64) {
              const size_t idx = ((size_t)((b_ * 64 + h) * 64 + w)) * 768 + col;
              fout[idx] = fin[idx] + v;
            }
          }
        } else if constexpr (EPI == 2) {
          const float gl = 0.5f * v * (1.f + erff(v * 0.70710678118f));
          ob0[(size_t)row * 3072 + col] = __float2bfloat16(gl);
        } else {
          const size_t idx = (size_t)row * 768 + col;
          fout[idx] = fin[idx] + v;
        }
      }
    }
  }
}

// ---------------- fused window attention, one block per (window, head) -------
// q/k/v: bf16 [2400][NPR][64]  (rows 196..207 garbage; masked/discarded)
// out:   bf16 [39200][768]  (col = head*64 + d)
// Static LDS: rel tables 2*196*14*4 = 21952 B, V^T 64*224*2 = 28672 B,
// per-wave P group tile 4*16*64*2 = 8192 B  -> total 58816 B (< 64 KB)
__global__ __launch_bounds__(256)
void attn_kernel(const bf16* __restrict__ qb, const bf16* __restrict__ kb,
                 const bf16* __restrict__ vb, const float* __restrict__ rph,
                 const float* __restrict__ rpw, bf16* __restrict__ aout) {
  __shared__ __align__(16) float relh[196 * 14];
  __shared__ __align__(16) float relw[196 * 14];
  __shared__ __align__(16) bf16 vt[64 * NPK];      // [64 d][224 keys]
  __shared__ __align__(16) bf16 pb[4][16 * 64];    // per-wave [16 q][64 keys]

  const int bh = blockIdx.x;             // 0..2399
  const int win = bh / 12, head = bh % 12;
  const bf16* Q = qb + (size_t)bh * NPR * 64;
  const bf16* Kp = kb + (size_t)bh * NPR * 64;
  const bf16* Vp = vb + (size_t)bh * NPR * 64;
  const int tid = threadIdx.x, lane = tid & 63, wv = tid >> 6;
  const int lr = lane & 15, hi = lane >> 4;
  bf16* pw = pb[wv];

  // stage V transposed (coalesced global read, scattered LDS write)
  for (int idx = tid; idx < 196 * 64; idx += 256) {
    const int key = idx >> 6, d = idx & 63;
    vt[d * NPK + key] = Vp[idx];
  }
  for (int idx = tid; idx < 64 * (NPK - 196); idx += 256) {
    const int d = idx / (NPK - 196), key = 196 + idx % (NPK - 196);
    vt[d * NPK + key] = __float2bfloat16(0.f);
  }
  // decomposed rel-pos tables: relh[q][kh] = q_vec . rel_pos_h[qh-kh+13]
  for (int idx = tid; idx < 196 * 14; idx += 256) {
    const int row = idx / 14, kk = idx % 14;
    const int qh = row / 14, qw = row % 14;
    const bf16* qr = Q + row * 64;
    const float* ph = rph + (qh - kk + 13) * 64;
    const float* pw2 = rpw + (qw - kk + 13) * 64;
    float sh = 0.f, sw = 0.f;
    for (int c = 0; c < 64; ++c) {
      const float qv = __bfloat162float(qr[c]);
      sh += qv * ph[c]; sw += qv * pw2[c];
    }
    relh[idx] = sh; relw[idx] = sw;
  }
  __syncthreads();

  for (int qt = wv; qt < 13; qt += 4) {
    // Q fragments for this 16-row q tile (direct from global, 16B/lane)
    short8 aq0 = *(const short8*)&Q[(qt * 16 + lr) * 64 + hi * 8];
    short8 aq1 = *(const short8*)&Q[(qt * 16 + lr) * 64 + 32 + hi * 8];
    // S = Q.K^T  (13 key tiles of 16)
    f32x4 s[13];
    #pragma unroll
    for (int nt = 0; nt < 13; ++nt) {
      f32x4 z = {};
      const short8 b0 = *(const short8*)&Kp[(nt * 16 + lr) * 64 + hi * 8];
      const short8 b1 = *(const short8*)&Kp[(nt * 16 + lr) * 64 + 32 + hi * 8];
      z = mfma16x16x32(aq0, b0, z);
      z = mfma16x16x32(aq1, b1, z);
      s[nt] = z;
    }
    // bias + mask, then wave-parallel softmax (row lives in one 16-lane group)
    const int q = qt * 16 + hi * 4;      // + e
    float mx[4], sm[4];
    #pragma unroll
    for (int e = 0; e < 4; ++e) { mx[e] = -3.0e38f; sm[e] = 0.f; }
    #pragma unroll
    for (int nt = 0; nt < 13; ++nt) {
      const int key = nt * 16 + lr;
      #pragma unroll
      for (int e = 0; e < 4; ++e) {
        const int qc = (q + e < 196) ? (q + e) : 0;   // clamp garbage rows
        float v;
        if (key < 196) v = s[nt][e] * 0.125f + relh[qc * 14 + key / 14] + relw[qc * 14 + key % 14];
        else v = -3.0e38f;
        s[nt][e] = v;
        mx[e] = fmaxf(mx[e], v);
      }
    }
    #pragma unroll
    for (int e = 0; e < 4; ++e) {
      #pragma unroll
      for (int d2 = 1; d2 < 16; d2 <<= 1) mx[e] = fmaxf(mx[e], __shfl_xor(mx[e], d2));
    }
    #pragma unroll
    for (int nt = 0; nt < 13; ++nt)
      #pragma unroll
      for (int e = 0; e < 4; ++e) {
        const float p = __expf(s[nt][e] - mx[e]);
        s[nt][e] = p; sm[e] += p;
      }
    #pragma unroll
    for (int e = 0; e < 4; ++e) {
      #pragma unroll
      for (int d2 = 1; d2 < 16; d2 <<= 1) sm[e] += __shfl_xor(sm[e], d2);
      sm[e] = 1.f / sm[e];
    }
    // O = P.V in 4 key-groups of 64 (P staged per-group in per-wave LDS tile)
    f32x4 o[4] = {};
    #pragma unroll
    for (int g = 0; g < 4; ++g) {
      const int ntn = (g < 3) ? 4 : 1;     // group 3 covers keys 192..223
      #pragma unroll
      for (int t = 0; t < ntn; ++t) {
        const int nt = g * 4 + t;
        #pragma unroll
        for (int e = 0; e < 4; ++e)
          pw[(hi * 4 + e) * 64 + t * 16 + lr] = __float2bfloat16(s[nt][e] * sm[e]);
      }
      if (g == 3) {
        #pragma unroll
        for (int e = 0; e < 4; ++e)
          pw[(hi * 4 + e) * 64 + 16 + lr] = __float2bfloat16(0.f);
      }
      const int nc = (g < 3) ? 2 : 1;
      #pragma unroll
      for (int c = 0; c < nc; ++c) {
        const short8 pa = *(const short8*)&pw[lr * 64 + c * 32 + hi * 8];
        #pragma unroll
        for (int n2 = 0; n2 < 4; ++n2) {
          const short8 vf = *(const short8*)&vt[(n2 * 16 + lr) * NPK + g * 64 + c * 32 + hi * 8];
          o[n2] = mfma16x16x32(pa, vf, o[n2]);
        }
      }
    }
    // scatter O -> [win*196+q][head*64+d]
    #pragma unroll
    for (int n2 = 0; n2 < 4; ++n2)
      #pragma unroll
      for (int e = 0; e < 4; ++e) {
        const int qe = q + e;
        if (qe < 196) {
          const int d = n2 * 16 + lr;
          aout[((size_t)(win * 196 + qe)) * 768 + head * 64 + d] = __float2bfloat16(o[n2][e]);
        }
      }
  }
}

// ---------------- host ----------------
extern "C" void kernel_launch(void* const* d_in, const int* in_sizes, int n_in,
                              void* d_out, int out_size, void* d_ws, size_t ws_size,
                              hipStream_t stream) {
  (void)in_sizes; (void)n_in; (void)out_size; (void)ws_size;
  const float* x      = (const float*)d_in[0];
  const float* ln1_g  = (const float*)d_in[1];
  const float* ln1_b  = (const float*)d_in[2];
  const float* qkv_w  = (const float*)d_in[3];
  const float* qkv_b  = (const float*)d_in[4];
  const float* proj_w = (const float*)d_in[5];
  const float* proj_b = (const float*)d_in[6];
  const float* rph    = (const float*)d_in[7];
  const float* rpw    = (const float*)d_in[8];
  const float* ln2_g  = (const float*)d_in[9];
  const float* ln2_b  = (const float*)d_in[10];
  const float* w1     = (const float*)d_in[11];
  const float* b1v    = (const float*)d_in[12];
  const float* w2     = (const float*)d_in[13];
  const float* b2v    = (const float*)d_in[14];
  float* outp = (float*)d_out;   // also serves as x1 (written by proj epilogue)

  // -------- workspace layout with liveness-based aliasing (~276 MB) --------
  char* ws = (char*)d_ws;
  size_t off = 0;
  auto alloc = [&](size_t bytes) { char* p = ws + off; off += (bytes + 255) & ~(size_t)255; return p; };
  bf16* qkv_wt  = (bf16*)alloc((size_t)2304 * 768 * 2);
  bf16* proj_wt = (bf16*)alloc((size_t)768 * 768 * 2);
  bf16* w1t     = (bf16*)alloc((size_t)3072 * 768 * 2);
  bf16* w2t     = (bf16*)alloc((size_t)768 * 3072 * 2);
  // region B: xnwin (qkv phase) -> attnout (proj phase) -> xn2 (mlp phase)
  const size_t szB1 = (size_t)MPAD * 768 * 2;          // xnwin / attnout
  const size_t szB2 = (size_t)TOK2 * 768 * 2;          // xn2
  char* regB = alloc(szB1 > szB2 ? szB1 : szB2);
  // region C: q/k/v (attn phase) -> hbuf (mlp phase)
  const size_t szQKV = (size_t)3 * 2400 * NPR * 64 * 2;
  const size_t szH   = (size_t)TOK2 * 3072 * 2;
  char* regC = alloc(szQKV > szH ? szQKV : szH);

  bf16* xnwin   = (bf16*)regB;
  bf16* attnout = (bf16*)regB;
  bf16* xn2     = (bf16*)regB;
  bf16* qbuf    = (bf16*)regC;
  bf16* kbuf    = qbuf + (size_t)2400 * NPR * 64;
  bf16* vbuf    = kbuf + (size_t)2400 * NPR * 64;
  bf16* hbuf    = (bf16*)regC;

  // weights -> bf16 transposed [N][K]
  transpose_cast<<<dim3(2304 / 32, 768 / 32), 256, 0, stream>>>(qkv_w, qkv_wt, 768, 2304);
  transpose_cast<<<dim3(768 / 32, 768 / 32), 256, 0, stream>>>(proj_w, proj_wt, 768, 768);
  transpose_cast<<<dim3(3072 / 32, 768 / 32), 256, 0, stream>>>(w1, w1t, 768, 3072);
  transpose_cast<<<dim3(768 / 32, 3072 / 32), 256, 0, stream>>>(w2, w2t, 3072, 768);

  // LN1 + window partition
  ln1_partition<<<dim3(MROWS / 4), 256, 0, stream>>>(x, ln1_g, ln1_b, xnwin);

  // qkv GEMM [39296 x 2304] = xnwin @ qkv_w, scatter to q/k/v
  gemm_bf16<0><<<dim3(2304 / 128, MPAD / 128), 256, 0, stream>>>(
      xnwin, qkv_wt, qkv_b, 768, MROWS, nullptr, nullptr, qbuf, kbuf, vbuf);

  // attention (writes attnout, which aliases xnwin -- xnwin is dead now)
  attn_kernel<<<dim3(2400), 256, 0, stream>>>(qbuf, kbuf, vbuf, rph, rpw, attnout);

  // proj GEMM + unpartition + residual -> x1 (= outp, f32)
  gemm_bf16<1><<<dim3(768 / 128, MPAD / 128), 256, 0, stream>>>(
      attnout, proj_wt, proj_b, 768, MROWS, x, outp, nullptr, nullptr, nullptr);

  // LN2 (writes xn2, aliases attnout -- dead now)
  ln2_kernel<<<dim3(TOK2 / 4), 256, 0, stream>>>(outp, ln2_g, ln2_b, xn2);

  // MLP (hbuf aliases q/k/v -- dead now)
  gemm_bf16<2><<<dim3(3072 / 128, TOK2 / 128), 256, 0, stream>>>(
      xn2, w1t, b1v, 768, TOK2, nullptr, nullptr, hbuf, nullptr, nullptr);
  gemm_bf16<3><<<dim3(768 / 128, TOK2 / 128), 256, 0, stream>>>(
      hbuf, w2t, b2v, 3072, TOK2, outp, outp, nullptr, nullptr, nullptr);
}

// Round 3
// 1512.257 us; speedup vs baseline: 1.1622x; 1.1622x over previous
//
#include <hip/hip_runtime.h>
#include <hip/hip_bf16.h>
#include <cstdint>
#include <cstddef>

using bf16 = __hip_bfloat16;
typedef __attribute__((ext_vector_type(8))) short short8;
typedef __attribute__((ext_vector_type(4))) float f32x4;

typedef __attribute__((address_space(1))) const void as1_void;
typedef __attribute__((address_space(3))) void as3_void;

__device__ __forceinline__ f32x4 mfma16x16x32(short8 a, short8 b, f32x4 c) {
  return __builtin_amdgcn_mfma_f32_16x16x32_bf16(a, b, c, 0, 0, 0);
}

__device__ __forceinline__ void gload_lds16(const void* g, void* l) {
  __builtin_amdgcn_global_load_lds((as1_void*)g, (as3_void*)l, 16, 0, 0);
}

// ---------------- problem constants ----------------
// B=8, H=W=64, C=768, NH=12, HD=64, WS=14 -> Hp=Wp=70, 5x5 windows, Bn=200
// N=196 tokens/window, padded rows NPR=208 (13x16), padded keys NPK=224 (7x32)

static constexpr int MROWS = 39200;
static constexpr int MPAD  = 39296;
static constexpr int TOK2  = 32768;
static constexpr int NPR   = 208;
static constexpr int NPK   = 224;
static constexpr int NPKP  = 232;   // padded V^T row stride (29*16B -> b128 spread)
static constexpr int PBS   = 72;    // padded P row stride (36 dw, odd/4 -> group spread)

// ---------------- weight transpose+cast:  in f32 [K][N] -> out bf16 [N][K] ----
__global__ __launch_bounds__(256)
void transpose_cast(const float* __restrict__ in, bf16* __restrict__ out, int K, int N) {
  __shared__ float t[32][33];
  const int tx = threadIdx.x & 31, ty = threadIdx.x >> 5;
  const int bx = blockIdx.x, by = blockIdx.y;   // bx: N-tile, by: K-tile
  const int x = bx * 32 + tx;
  for (int r = ty; r < 32; r += 8)
    t[r][tx] = in[(size_t)(by * 32 + r) * N + x];
  __syncthreads();
  const int xo = by * 32 + tx;
  for (int r = ty; r < 32; r += 8)
    out[(size_t)(bx * 32 + r) * K + xo] = __float2bfloat16(t[tx][r]);
}

// ---------------- LN1 + window partition -> bf16 [MPAD][768] ----------------
__global__ __launch_bounds__(256)
void ln1_partition(const float* __restrict__ x, const float* __restrict__ g,
                   const float* __restrict__ bb, bf16* __restrict__ out) {
  const int token = blockIdx.x * 4 + (threadIdx.x >> 6);  // < 39200
  const int lane = threadIdx.x & 63;
  const int win = token / 196, tok = token % 196;
  const int b_ = win / 25, wh = (win / 5) % 5, ww = win % 5;
  const int i = tok / 14, j = tok % 14;
  const int h = wh * 14 + i, w = ww * 14 + j;
  bf16* o = out + (size_t)token * 768;
  if (h >= 64 || w >= 64) {
    for (int t = 0; t < 12; ++t) o[lane + 64 * t] = __float2bfloat16(0.f);
    return;
  }
  const float* src = x + ((size_t)((b_ * 64 + h) * 64 + w)) * 768;
  float vals[12], s = 0.f, ss = 0.f;
  #pragma unroll
  for (int t = 0; t < 12; ++t) {
    float v = src[lane + 64 * t];
    vals[t] = v; s += v; ss += v * v;
  }
  #pragma unroll
  for (int d = 32; d > 0; d >>= 1) { s += __shfl_xor(s, d); ss += __shfl_xor(ss, d); }
  const float mu = s * (1.f / 768.f);
  const float var = ss * (1.f / 768.f) - mu * mu;
  const float inv = rsqrtf(var + 1e-6f);
  #pragma unroll
  for (int t = 0; t < 12; ++t) {
    const int c = lane + 64 * t;
    o[c] = __float2bfloat16((vals[t] - mu) * inv * g[c] + bb[c]);
  }
}

// ---------------- LN2 on x1 (f32, dense [32768][768]) -> bf16 ----------------
__global__ __launch_bounds__(256)
void ln2_kernel(const float* __restrict__ x1, const float* __restrict__ g,
                const float* __restrict__ bb, bf16* __restrict__ out) {
  const int token = blockIdx.x * 4 + (threadIdx.x >> 6);  // < 32768
  const int lane = threadIdx.x & 63;
  const float* src = x1 + (size_t)token * 768;
  bf16* o = out + (size_t)token * 768;
  float vals[12], s = 0.f, ss = 0.f;
  #pragma unroll
  for (int t = 0; t < 12; ++t) {
    float v = src[lane + 64 * t];
    vals[t] = v; s += v; ss += v * v;
  }
  #pragma unroll
  for (int d = 32; d > 0; d >>= 1) { s += __shfl_xor(s, d); ss += __shfl_xor(ss, d); }
  const float mu = s * (1.f / 768.f);
  const float var = ss * (1.f / 768.f) - mu * mu;
  const float inv = rsqrtf(var + 1e-6f);
  #pragma unroll
  for (int t = 0; t < 12; ++t) {
    const int c = lane + 64 * t;
    o[c] = __float2bfloat16((vals[t] - mu) * inv * g[c] + bb[c]);
  }
}

// ---------------- generic bf16 GEMM, 128x128 tile, BK=32, fused epilogues ----
template<int EPI>
__global__ __launch_bounds__(256)
void gemm_bf16(const bf16* __restrict__ A, const bf16* __restrict__ Bt,
               const float* __restrict__ bias, int K, int Mreal,
               const float* __restrict__ fin, float* __restrict__ fout,
               bf16* __restrict__ ob0, bf16* __restrict__ ob1, bf16* __restrict__ ob2) {
  __shared__ __align__(16) bf16 lA[128 * 32];
  __shared__ __align__(16) bf16 lB[128 * 32];
  const int tid = threadIdx.x;
  const int lane = tid & 63, wv = tid >> 6;
  const int lr = lane & 15, hi = lane >> 4;
  const int wm = wv >> 1, wn = wv & 1;
  const size_t arow0 = (size_t)blockIdx.y * 128;
  const size_t brow0 = (size_t)blockIdx.x * 128;
  f32x4 acc[4][4] = {};
  for (int k0 = 0; k0 < K; k0 += 32) {
    #pragma unroll
    for (int it = 0; it < 2; ++it) {
      const int seg = it * 256 + tid;
      const int row = seg >> 2, kq = seg & 3;
      gload_lds16(A + (arow0 + row) * K + k0 + kq * 8, &lA[(size_t)(it * 256 + wv * 64) * 8]);
      gload_lds16(Bt + (brow0 + row) * K + k0 + kq * 8, &lB[(size_t)(it * 256 + wv * 64) * 8]);
    }
    __syncthreads();
    short8 af[4], bfr[4];
    #pragma unroll
    for (int m = 0; m < 4; ++m) af[m] = *(const short8*)&lA[(wm * 64 + m * 16 + lr) * 32 + hi * 8];
    #pragma unroll
    for (int n = 0; n < 4; ++n) bfr[n] = *(const short8*)&lB[(wn * 64 + n * 16 + lr) * 32 + hi * 8];
    #pragma unroll
    for (int m = 0; m < 4; ++m)
      #pragma unroll
      for (int n = 0; n < 4; ++n)
        acc[m][n] = mfma16x16x32(af[m], bfr[n], acc[m][n]);
    __syncthreads();
  }
  // epilogue
  #pragma unroll
  for (int n = 0; n < 4; ++n) {
    const int col = (int)brow0 + wn * 64 + n * 16 + lr;
    const float bv = bias[col];
    #pragma unroll
    for (int m = 0; m < 4; ++m) {
      #pragma unroll
      for (int e = 0; e < 4; ++e) {
        const int row = (int)arow0 + wm * 64 + m * 16 + hi * 4 + e;
        const float v = acc[m][n][e] + bv;
        if constexpr (EPI == 0) {
          if (row < Mreal) {
            const int win = row / 196, tok = row % 196;
            const int which = col / 768, head = (col >> 6) % 12, d = col & 63;
            bf16* dst = (which == 0) ? ob0 : ((which == 1) ? ob1 : ob2);
            dst[((size_t)(win * 12 + head) * NPR + tok) * 64 + d] = __float2bfloat16(v);
          }
        } else if constexpr (EPI == 1) {
          if (row < Mreal) {
            const int win = row / 196, tok = row % 196;
            const int b_ = win / 25, wh = (win / 5) % 5, ww = win % 5;
            const int i = tok / 14, j = tok % 14;
            const int h = wh * 14 + i, w = ww * 14 + j;
            if (h < 64 && w < 64) {
              const size_t idx = ((size_t)((b_ * 64 + h) * 64 + w)) * 768 + col;
              fout[idx] = fin[idx] + v;
            }
          }
        } else if constexpr (EPI == 2) {
          const float gl = 0.5f * v * (1.f + erff(v * 0.70710678118f));
          ob0[(size_t)row * 3072 + col] = __float2bfloat16(gl);
        } else {
          const size_t idx = (size_t)row * 768 + col;
          fout[idx] = fin[idx] + v;
        }
      }
    }
  }
}

// ---------------- fused window attention, one block per (window, head) -------
// q/k/v: bf16 [2400][NPR][64]  (rows 196..207 stale; masked/discarded)
// out:   bf16 [39200][768]  (col = head*64 + d)
//
// Rel-pos bias via factorization: Gh = Q @ rph^T (196x27), relh[q][kh]=Gh[q][qh-kh+13]
// LDS: union region U (38912 B) phase-aliased:
//   phase A: pbh[32][64] | pbw[32][64] | Gh[208][36] | Gw[208][36]   (38144 B)
//   phase C+: vt[64][NPKP] (29696 B) | pb[4][16][PBS] (9216 B)
// plus persistent relh/relw bf16 [196][14] (10976 B).  Total 49888 B -> 3 blocks/CU.
__global__ __launch_bounds__(256, 3)
void attn_kernel(const bf16* __restrict__ qb, const bf16* __restrict__ kb,
                 const bf16* __restrict__ vb, const float* __restrict__ rph,
                 const float* __restrict__ rpw, bf16* __restrict__ aout) {
  __shared__ __align__(16) char U[38912];
  __shared__ __align__(16) bf16 relh_s[196 * 14];
  __shared__ __align__(16) bf16 relw_s[196 * 14];
  bf16* pbh = (bf16*)U;                       // [32][64]
  bf16* pbw = (bf16*)(U + 4096);              // [32][64]
  bf16* Gh  = (bf16*)(U + 8192);              // [208][36]
  bf16* Gw  = (bf16*)(U + 8192 + 14976);      // [208][36]
  bf16* vt  = (bf16*)U;                       // [64][NPKP]
  bf16* pb  = (bf16*)(U + 29696);             // [4][16][PBS]

  const int bh = blockIdx.x;             // 0..2399
  const int win = bh / 12, head = bh % 12;
  const bf16* Q  = qb + (size_t)bh * NPR * 64;
  const bf16* Kp = kb + (size_t)bh * NPR * 64;
  const bf16* Vp = vb + (size_t)bh * NPR * 64;
  const int tid = threadIdx.x, lane = tid & 63, wv = tid >> 6;
  const int lr = lane & 15, hi = lane >> 4;
  bf16* pw = pb + wv * 16 * PBS;

  // ---- phase A: stage rel_pos (bf16, zero-padded to 32 rows), compute G ----
  for (int i = tid; i < 32 * 64; i += 256) {
    const int r = i >> 6, c = i & 63;
    const bool ok = r < 27;
    pbh[i] = __float2bfloat16(ok ? rph[r * 64 + c] : 0.f);
    pbw[i] = __float2bfloat16(ok ? rpw[r * 64 + c] : 0.f);
  }
  __syncthreads();
  {
    short8 bh00 = *(const short8*)&pbh[(lr) * 64 + hi * 8];
    short8 bh01 = *(const short8*)&pbh[(lr) * 64 + 32 + hi * 8];
    short8 bh10 = *(const short8*)&pbh[(16 + lr) * 64 + hi * 8];
    short8 bh11 = *(const short8*)&pbh[(16 + lr) * 64 + 32 + hi * 8];
    short8 bw00 = *(const short8*)&pbw[(lr) * 64 + hi * 8];
    short8 bw01 = *(const short8*)&pbw[(lr) * 64 + 32 + hi * 8];
    short8 bw10 = *(const short8*)&pbw[(16 + lr) * 64 + hi * 8];
    short8 bw11 = *(const short8*)&pbw[(16 + lr) * 64 + 32 + hi * 8];
    for (int mt = wv; mt < 13; mt += 4) {
      const short8 a0 = *(const short8*)&Q[(mt * 16 + lr) * 64 + hi * 8];
      const short8 a1 = *(const short8*)&Q[(mt * 16 + lr) * 64 + 32 + hi * 8];
      f32x4 g0 = {}, g1 = {}, g2 = {}, g3 = {};
      g0 = mfma16x16x32(a0, bh00, g0); g0 = mfma16x16x32(a1, bh01, g0);
      g1 = mfma16x16x32(a0, bh10, g1); g1 = mfma16x16x32(a1, bh11, g1);
      g2 = mfma16x16x32(a0, bw00, g2); g2 = mfma16x16x32(a1, bw01, g2);
      g3 = mfma16x16x32(a0, bw10, g3); g3 = mfma16x16x32(a1, bw11, g3);
      #pragma unroll
      for (int e = 0; e < 4; ++e) {
        const int row = mt * 16 + hi * 4 + e;
        Gh[row * 36 + lr]      = __float2bfloat16(g0[e]);
        Gh[row * 36 + 16 + lr] = __float2bfloat16(g1[e]);
        Gw[row * 36 + lr]      = __float2bfloat16(g2[e]);
        Gw[row * 36 + 16 + lr] = __float2bfloat16(g3[e]);
      }
    }
  }
  __syncthreads();

  // ---- phase B: gather G -> regs (rel tables), then release G region ----
  bf16 ghr[11], gwr[11];
  #pragma unroll
  for (int t = 0; t < 11; ++t) {
    const int i = tid + t * 256;
    if (i < 196 * 14) {
      const int q = i / 14, kk = i - (i / 14) * 14;
      const int rh = q / 14 - kk + 13;
      const int rw2 = q - (q / 14) * 14 - kk + 13;
      ghr[t] = Gh[q * 36 + rh];
      gwr[t] = Gw[q * 36 + rw2];
    }
  }
  __syncthreads();

  // ---- phase C: write rel tables; stage V^T; zero P pad cols ----
  #pragma unroll
  for (int t = 0; t < 11; ++t) {
    const int i = tid + t * 256;
    if (i < 196 * 14) { relh_s[i] = ghr[t]; relw_s[i] = gwr[t]; }
  }
  for (int i = tid; i < 196 * 64; i += 256) {
    const int key = i >> 6, d = i & 63;
    vt[d * NPKP + key] = Vp[i];
  }
  for (int i = tid; i < 64 * (NPK - 196); i += 256) {
    const int d = i / (NPK - 196), key = 196 + i % (NPK - 196);
    vt[d * NPKP + key] = __float2bfloat16(0.f);
  }
  // zero keys 208..223 of every P tile (group 3 cols 16..31)
  {
    const int w2 = wv;
    #pragma unroll
    for (int e = 0; e < 4; ++e)
      pb[w2 * 16 * PBS + (hi * 4 + e) * PBS + 16 + lr] = __float2bfloat16(0.f);
  }
  __syncthreads();

  // ---- main loop over q-tiles ----
  for (int qt = wv; qt < 13; qt += 4) {
    const short8 aq0 = *(const short8*)&Q[(qt * 16 + lr) * 64 + hi * 8];
    const short8 aq1 = *(const short8*)&Q[(qt * 16 + lr) * 64 + 32 + hi * 8];
    // S = Q.K^T  (13 key tiles of 16)
    f32x4 s[13];
    #pragma unroll
    for (int nt = 0; nt < 13; ++nt) {
      f32x4 z = {};
      const short8 b0 = *(const short8*)&Kp[(nt * 16 + lr) * 64 + hi * 8];
      const short8 b1 = *(const short8*)&Kp[(nt * 16 + lr) * 64 + 32 + hi * 8];
      z = mfma16x16x32(aq0, b0, z);
      z = mfma16x16x32(aq1, b1, z);
      s[nt] = z;
    }
    const int q = qt * 16 + hi * 4;      // + e
    float mx[4], sm[4];
    #pragma unroll
    for (int e = 0; e < 4; ++e) { mx[e] = -3.0e38f; sm[e] = 0.f; }
    #pragma unroll
    for (int nt = 0; nt < 13; ++nt) {
      const int key = nt * 16 + lr;
      const int kh = key / 14;
      const int kw = key - kh * 14;
      #pragma unroll
      for (int e = 0; e < 4; ++e) {
        const int qc = (q + e < 196) ? (q + e) : 0;   // clamp stale rows
        float v;
        if (key < 196)
          v = s[nt][e] * 0.125f + __bfloat162float(relh_s[qc * 14 + kh])
                                + __bfloat162float(relw_s[qc * 14 + kw]);
        else v = -3.0e38f;
        s[nt][e] = v;
        mx[e] = fmaxf(mx[e], v);
      }
    }
    #pragma unroll
    for (int e = 0; e < 4; ++e) {
      #pragma unroll
      for (int d2 = 1; d2 < 16; d2 <<= 1) mx[e] = fmaxf(mx[e], __shfl_xor(mx[e], d2));
    }
    #pragma unroll
    for (int nt = 0; nt < 13; ++nt)
      #pragma unroll
      for (int e = 0; e < 4; ++e) {
        const float p = __expf(s[nt][e] - mx[e]);
        s[nt][e] = p; sm[e] += p;
      }
    #pragma unroll
    for (int e = 0; e < 4; ++e) {
      #pragma unroll
      for (int d2 = 1; d2 < 16; d2 <<= 1) sm[e] += __shfl_xor(sm[e], d2);
      sm[e] = 1.f / sm[e];
    }
    // O = P.V in 4 key-groups of 64 (P staged per-group in per-wave LDS tile)
    f32x4 o[4] = {};
    #pragma unroll
    for (int g = 0; g < 4; ++g) {
      const int ntn = (g < 3) ? 4 : 1;     // group 3 covers keys 192..223
      #pragma unroll
      for (int t = 0; t < ntn; ++t) {
        const int nt = g * 4 + t;
        #pragma unroll
        for (int e = 0; e < 4; ++e)
          pw[(hi * 4 + e) * PBS + t * 16 + lr] = __float2bfloat16(s[nt][e] * sm[e]);
      }
      const int nc = (g < 3) ? 2 : 1;
      #pragma unroll
      for (int c = 0; c < nc; ++c) {
        const short8 pa = *(const short8*)&pw[lr * PBS + c * 32 + hi * 8];
        #pragma unroll
        for (int n2 = 0; n2 < 4; ++n2) {
          const short8 vf = *(const short8*)&vt[(n2 * 16 + lr) * NPKP + g * 64 + c * 32 + hi * 8];
          o[n2] = mfma16x16x32(pa, vf, o[n2]);
        }
      }
    }
    // scatter O -> [win*196+q][head*64+d]
    #pragma unroll
    for (int n2 = 0; n2 < 4; ++n2)
      #pragma unroll
      for (int e = 0; e < 4; ++e) {
        const int qe = q + e;
        if (qe < 196) {
          const int d = n2 * 16 + lr;
          aout[((size_t)(win * 196 + qe)) * 768 + head * 64 + d] = __float2bfloat16(o[n2][e]);
        }
      }
  }
}

// ---------------- host ----------------
extern "C" void kernel_launch(void* const* d_in, const int* in_sizes, int n_in,
                              void* d_out, int out_size, void* d_ws, size_t ws_size,
                              hipStream_t stream) {
  (void)in_sizes; (void)n_in; (void)out_size; (void)ws_size;
  const float* x      = (const float*)d_in[0];
  const float* ln1_g  = (const float*)d_in[1];
  const float* ln1_b  = (const float*)d_in[2];
  const float* qkv_w  = (const float*)d_in[3];
  const float* qkv_b  = (const float*)d_in[4];
  const float* proj_w = (const float*)d_in[5];
  const float* proj_b = (const float*)d_in[6];
  const float* rph    = (const float*)d_in[7];
  const float* rpw    = (const float*)d_in[8];
  const float* ln2_g  = (const float*)d_in[9];
  const float* ln2_b  = (const float*)d_in[10];
  const float* w1     = (const float*)d_in[11];
  const float* b1v    = (const float*)d_in[12];
  const float* w2     = (const float*)d_in[13];
  const float* b2v    = (const float*)d_in[14];
  float* outp = (float*)d_out;   // also serves as x1 (written by proj epilogue)

  // -------- workspace layout with liveness-based aliasing (~276 MB) --------
  char* ws = (char*)d_ws;
  size_t off = 0;
  auto alloc = [&](size_t bytes) { char* p = ws + off; off += (bytes + 255) & ~(size_t)255; return p; };
  bf16* qkv_wt  = (bf16*)alloc((size_t)2304 * 768 * 2);
  bf16* proj_wt = (bf16*)alloc((size_t)768 * 768 * 2);
  bf16* w1t     = (bf16*)alloc((size_t)3072 * 768 * 2);
  bf16* w2t     = (bf16*)alloc((size_t)768 * 3072 * 2);
  // region B: xnwin (qkv phase) -> attnout (proj phase) -> xn2 (mlp phase)
  const size_t szB1 = (size_t)MPAD * 768 * 2;          // xnwin / attnout
  const size_t szB2 = (size_t)TOK2 * 768 * 2;          // xn2
  char* regB = alloc(szB1 > szB2 ? szB1 : szB2);
  // region C: q/k/v (attn phase) -> hbuf (mlp phase)
  const size_t szQKV = (size_t)3 * 2400 * NPR * 64 * 2;
  const size_t szH   = (size_t)TOK2 * 3072 * 2;
  char* regC = alloc(szQKV > szH ? szQKV : szH);

  bf16* xnwin   = (bf16*)regB;
  bf16* attnout = (bf16*)regB;
  bf16* xn2     = (bf16*)regB;
  bf16* qbuf    = (bf16*)regC;
  bf16* kbuf    = qbuf + (size_t)2400 * NPR * 64;
  bf16* vbuf    = kbuf + (size_t)2400 * NPR * 64;
  bf16* hbuf    = (bf16*)regC;

  // weights -> bf16 transposed [N][K]
  transpose_cast<<<dim3(2304 / 32, 768 / 32), 256, 0, stream>>>(qkv_w, qkv_wt, 768, 2304);
  transpose_cast<<<dim3(768 / 32, 768 / 32), 256, 0, stream>>>(proj_w, proj_wt, 768, 768);
  transpose_cast<<<dim3(3072 / 32, 768 / 32), 256, 0, stream>>>(w1, w1t, 768, 3072);
  transpose_cast<<<dim3(768 / 32, 3072 / 32), 256, 0, stream>>>(w2, w2t, 3072, 768);

  // LN1 + window partition
  ln1_partition<<<dim3(MROWS / 4), 256, 0, stream>>>(x, ln1_g, ln1_b, xnwin);

  // qkv GEMM [39296 x 2304] = xnwin @ qkv_w, scatter to q/k/v
  gemm_bf16<0><<<dim3(2304 / 128, MPAD / 128), 256, 0, stream>>>(
      xnwin, qkv_wt, qkv_b, 768, MROWS, nullptr, nullptr, qbuf, kbuf, vbuf);

  // attention (writes attnout, which aliases xnwin -- xnwin is dead now)
  attn_kernel<<<dim3(2400), 256, 0, stream>>>(qbuf, kbuf, vbuf, rph, rpw, attnout);

  // proj GEMM + unpartition + residual -> x1 (= outp, f32)
  gemm_bf16<1><<<dim3(768 / 128, MPAD / 128), 256, 0, stream>>>(
      attnout, proj_wt, proj_b, 768, MROWS, x, outp, nullptr, nullptr, nullptr);

  // LN2 (writes xn2, aliases attnout -- dead now)
  ln2_kernel<<<dim3(TOK2 / 4), 256, 0, stream>>>(outp, ln2_g, ln2_b, xn2);

  // MLP (hbuf aliases q/k/v -- dead now)
  gemm_bf16<2><<<dim3(3072 / 128, TOK2 / 128), 256, 0, stream>>>(
      xn2, w1t, b1v, 768, TOK2, nullptr, nullptr, hbuf, nullptr, nullptr);
  gemm_bf16<3><<<dim3(768 / 128, TOK2 / 128), 256, 0, stream>>>(
      hbuf, w2t, b2v, 3072, TOK2, outp, outp, nullptr, nullptr, nullptr);
}

// Round 4
// 1419.395 us; speedup vs baseline: 1.2383x; 1.0654x over previous
//
#include <hip/hip_runtime.h>
#include <hip/hip_bf16.h>
#include <cstdint>
#include <cstddef>

using bf16 = __hip_bfloat16;
typedef __attribute__((ext_vector_type(8))) short short8;
typedef __attribute__((ext_vector_type(4))) float f32x4;

typedef __attribute__((address_space(1))) const void as1_void;
typedef __attribute__((address_space(3))) void as3_void;

__device__ __forceinline__ f32x4 mfma16x16x32(short8 a, short8 b, f32x4 c) {
  return __builtin_amdgcn_mfma_f32_16x16x32_bf16(a, b, c, 0, 0, 0);
}

__device__ __forceinline__ void gload_lds16(const void* g, void* l) {
  __builtin_amdgcn_global_load_lds((as1_void*)g, (as3_void*)l, 16, 0, 0);
}

__device__ __forceinline__ uint32_t cvtpk(float a, float b) {
  uint32_t r;
  asm("v_cvt_pk_bf16_f32 %0, %1, %2" : "=v"(r) : "v"(a), "v"(b));
  return r;
}

// ---------------- problem constants ----------------
// B=8, H=W=64, C=768, NH=12, HD=64, WS=14 -> Hp=Wp=70, 5x5 windows, Bn=200
// N=196 tokens/window, padded rows NPR=208, padded keys NPK=224 (7x32)

static constexpr int MROWS = 39200;
static constexpr int MPAD  = 39296;
static constexpr int TOK2  = 32768;
static constexpr int NPR   = 208;

// ---------------- weight transpose+cast:  in f32 [K][N] -> out bf16 [N][K] ----
__global__ __launch_bounds__(256)
void transpose_cast(const float* __restrict__ in, bf16* __restrict__ out, int K, int N) {
  __shared__ float t[32][33];
  const int tx = threadIdx.x & 31, ty = threadIdx.x >> 5;
  const int bx = blockIdx.x, by = blockIdx.y;   // bx: N-tile, by: K-tile
  const int x = bx * 32 + tx;
  for (int r = ty; r < 32; r += 8)
    t[r][tx] = in[(size_t)(by * 32 + r) * N + x];
  __syncthreads();
  const int xo = by * 32 + tx;
  for (int r = ty; r < 32; r += 8)
    out[(size_t)(bx * 32 + r) * K + xo] = __float2bfloat16(t[tx][r]);
}

// ---------------- LN1 + window partition -> bf16 [MPAD][768] ----------------
__global__ __launch_bounds__(256)
void ln1_partition(const float* __restrict__ x, const float* __restrict__ g,
                   const float* __restrict__ bb, bf16* __restrict__ out) {
  const int token = blockIdx.x * 4 + (threadIdx.x >> 6);  // < 39200
  const int lane = threadIdx.x & 63;
  const int win = token / 196, tok = token % 196;
  const int b_ = win / 25, wh = (win / 5) % 5, ww = win % 5;
  const int i = tok / 14, j = tok % 14;
  const int h = wh * 14 + i, w = ww * 14 + j;
  bf16* o = out + (size_t)token * 768;
  if (h >= 64 || w >= 64) {
    for (int t = 0; t < 12; ++t) o[lane + 64 * t] = __float2bfloat16(0.f);
    return;
  }
  const float* src = x + ((size_t)((b_ * 64 + h) * 64 + w)) * 768;
  float vals[12], s = 0.f, ss = 0.f;
  #pragma unroll
  for (int t = 0; t < 12; ++t) {
    float v = src[lane + 64 * t];
    vals[t] = v; s += v; ss += v * v;
  }
  #pragma unroll
  for (int d = 32; d > 0; d >>= 1) { s += __shfl_xor(s, d); ss += __shfl_xor(ss, d); }
  const float mu = s * (1.f / 768.f);
  const float var = ss * (1.f / 768.f) - mu * mu;
  const float inv = rsqrtf(var + 1e-6f);
  #pragma unroll
  for (int t = 0; t < 12; ++t) {
    const int c = lane + 64 * t;
    o[c] = __float2bfloat16((vals[t] - mu) * inv * g[c] + bb[c]);
  }
}

// ---------------- LN2 on x1 (f32, dense [32768][768]) -> bf16 ----------------
__global__ __launch_bounds__(256)
void ln2_kernel(const float* __restrict__ x1, const float* __restrict__ g,
                const float* __restrict__ bb, bf16* __restrict__ out) {
  const int token = blockIdx.x * 4 + (threadIdx.x >> 6);  // < 32768
  const int lane = threadIdx.x & 63;
  const float* src = x1 + (size_t)token * 768;
  bf16* o = out + (size_t)token * 768;
  float vals[12], s = 0.f, ss = 0.f;
  #pragma unroll
  for (int t = 0; t < 12; ++t) {
    float v = src[lane + 64 * t];
    vals[t] = v; s += v; ss += v * v;
  }
  #pragma unroll
  for (int d = 32; d > 0; d >>= 1) { s += __shfl_xor(s, d); ss += __shfl_xor(ss, d); }
  const float mu = s * (1.f / 768.f);
  const float var = ss * (1.f / 768.f) - mu * mu;
  const float inv = rsqrtf(var + 1e-6f);
  #pragma unroll
  for (int t = 0; t < 12; ++t) {
    const int c = lane + 64 * t;
    o[c] = __float2bfloat16((vals[t] - mu) * inv * g[c] + bb[c]);
  }
}

// ---------------- generic bf16 GEMM, 128x128 tile, BK=32, fused epilogues ----
// EPI 0: qkv scatter; EPI 1: proj (A in [head][MPAD][64] layout) + residual;
// EPI 2: gelu -> bf16; EPI 3: dense residual add.
template<int EPI>
__global__ __launch_bounds__(256)
void gemm_bf16(const bf16* __restrict__ A, const bf16* __restrict__ Bt,
               const float* __restrict__ bias, int K, int Mreal,
               const float* __restrict__ fin, float* __restrict__ fout,
               bf16* __restrict__ ob0, bf16* __restrict__ ob1, bf16* __restrict__ ob2) {
  __shared__ __align__(16) bf16 lA[128 * 32];
  __shared__ __align__(16) bf16 lB[128 * 32];
  const int tid = threadIdx.x;
  const int lane = tid & 63, wv = tid >> 6;
  const int lr = lane & 15, hi = lane >> 4;
  const int wm = wv >> 1, wn = wv & 1;
  const size_t arow0 = (size_t)blockIdx.y * 128;
  const size_t brow0 = (size_t)blockIdx.x * 128;
  f32x4 acc[4][4] = {};
  for (int k0 = 0; k0 < K; k0 += 32) {
    #pragma unroll
    for (int it = 0; it < 2; ++it) {
      const int seg = it * 256 + tid;
      const int row = seg >> 2, kq = seg & 3;
      if constexpr (EPI == 1) {
        const int k = k0 + kq * 8;   // A layout: [head][MPAD][64]
        gload_lds16(A + ((size_t)(k >> 6) * MPAD + arow0 + row) * 64 + (k & 63),
                    &lA[(size_t)(it * 256 + wv * 64) * 8]);
      } else {
        gload_lds16(A + (arow0 + row) * K + k0 + kq * 8, &lA[(size_t)(it * 256 + wv * 64) * 8]);
      }
      gload_lds16(Bt + (brow0 + row) * K + k0 + kq * 8, &lB[(size_t)(it * 256 + wv * 64) * 8]);
    }
    __syncthreads();
    short8 af[4], bfr[4];
    #pragma unroll
    for (int m = 0; m < 4; ++m) af[m] = *(const short8*)&lA[(wm * 64 + m * 16 + lr) * 32 + hi * 8];
    #pragma unroll
    for (int n = 0; n < 4; ++n) bfr[n] = *(const short8*)&lB[(wn * 64 + n * 16 + lr) * 32 + hi * 8];
    #pragma unroll
    for (int m = 0; m < 4; ++m)
      #pragma unroll
      for (int n = 0; n < 4; ++n)
        acc[m][n] = mfma16x16x32(af[m], bfr[n], acc[m][n]);
    __syncthreads();
  }
  // epilogue
  #pragma unroll
  for (int n = 0; n < 4; ++n) {
    const int col = (int)brow0 + wn * 64 + n * 16 + lr;
    const float bv = bias[col];
    #pragma unroll
    for (int m = 0; m < 4; ++m) {
      #pragma unroll
      for (int e = 0; e < 4; ++e) {
        const int row = (int)arow0 + wm * 64 + m * 16 + hi * 4 + e;
        const float v = acc[m][n][e] + bv;
        if constexpr (EPI == 0) {
          if (row < Mreal) {
            const int win = row / 196, tok = row % 196;
            const int which = col / 768, head = (col >> 6) % 12, d = col & 63;
            bf16* dst = (which == 0) ? ob0 : ((which == 1) ? ob1 : ob2);
            dst[((size_t)(win * 12 + head) * NPR + tok) * 64 + d] = __float2bfloat16(v);
          }
        } else if constexpr (EPI == 1) {
          if (row < Mreal) {
            const int win = row / 196, tok = row % 196;
            const int b_ = win / 25, wh = (win / 5) % 5, ww = win % 5;
            const int i = tok / 14, j = tok % 14;
            const int h = wh * 14 + i, w = ww * 14 + j;
            if (h < 64 && w < 64) {
              const size_t idx = ((size_t)((b_ * 64 + h) * 64 + w)) * 768 + col;
              fout[idx] = fin[idx] + v;
            }
          }
        } else if constexpr (EPI == 2) {
          const float gl = 0.5f * v * (1.f + erff(v * 0.70710678118f));
          ob0[(size_t)row * 3072 + col] = __float2bfloat16(gl);
        } else {
          const size_t idx = (size_t)row * 768 + col;
          fout[idx] = fin[idx] + v;
        }
      }
    }
  }
}

// ---------------- fused window attention, one block per (window, head) -------
// Swapped-operand design: S^T = mfma(K, Q) so each lane owns one q-row (q = lr).
// P stays in registers (cvt_pk + 2-round shfl exchange), PV computed as O^T.
// LDS (static, 65248 B):
//   phase A (aliased):  pbh[32][64] @0 | pbw @4096 | Gh[208][36] @8192 | Gw @23168
//   main:   klds[200][64] swz @0 | vt[64][224] swz @25600 | relh @54272 | relw @59760
// out layout: aout[head][MPAD][64]
__global__ __launch_bounds__(256)
void attn_kernel(const bf16* __restrict__ qb, const bf16* __restrict__ kb,
                 const bf16* __restrict__ vb, const float* __restrict__ rph,
                 const float* __restrict__ rpw, bf16* __restrict__ aout) {
  __shared__ __align__(16) char SM[65248];
  bf16* pbh    = (bf16*)SM;
  bf16* pbw    = (bf16*)(SM + 4096);
  bf16* Gh     = (bf16*)(SM + 8192);
  bf16* Gw     = (bf16*)(SM + 23168);
  char* klds   = SM;                    // [200 rows][128 B], XOR-swizzled
  char* vtb    = SM + 25600;            // [64 d][448 B], XOR-swizzled
  bf16* relh_s = (bf16*)(SM + 54272);   // [196][14]
  bf16* relw_s = (bf16*)(SM + 59760);   // [196][14]

  const int bh = blockIdx.x;             // 0..2399
  const int win = bh / 12, head = bh % 12;
  const bf16* Q  = qb + (size_t)bh * NPR * 64;
  const bf16* Kp = kb + (size_t)bh * NPR * 64;
  const bf16* Vp = vb + (size_t)bh * NPR * 64;
  const int tid = threadIdx.x, lane = tid & 63, wv = tid >> 6;
  const int lr = lane & 15, hi = lane >> 4;

  // ---- phase A0: stage rel_pos tables (bf16, zero-padded to 32 rows) ----
  for (int i = tid; i < 32 * 64; i += 256) {
    const int r = i >> 6, c = i & 63;
    const bool ok = r < 27;
    pbh[i] = __float2bfloat16(ok ? rph[r * 64 + c] : 0.f);
    pbw[i] = __float2bfloat16(ok ? rpw[r * 64 + c] : 0.f);
  }
  __syncthreads();
  // ---- phase A: G = Q @ relpos^T via MFMA ----
  {
    short8 bh00 = *(const short8*)&pbh[(lr) * 64 + hi * 8];
    short8 bh01 = *(const short8*)&pbh[(lr) * 64 + 32 + hi * 8];
    short8 bh10 = *(const short8*)&pbh[(16 + lr) * 64 + hi * 8];
    short8 bh11 = *(const short8*)&pbh[(16 + lr) * 64 + 32 + hi * 8];
    short8 bw00 = *(const short8*)&pbw[(lr) * 64 + hi * 8];
    short8 bw01 = *(const short8*)&pbw[(lr) * 64 + 32 + hi * 8];
    short8 bw10 = *(const short8*)&pbw[(16 + lr) * 64 + hi * 8];
    short8 bw11 = *(const short8*)&pbw[(16 + lr) * 64 + 32 + hi * 8];
    for (int mt = wv; mt < 13; mt += 4) {
      const short8 a0 = *(const short8*)&Q[(mt * 16 + lr) * 64 + hi * 8];
      const short8 a1 = *(const short8*)&Q[(mt * 16 + lr) * 64 + 32 + hi * 8];
      f32x4 g0 = {}, g1 = {}, g2 = {}, g3 = {};
      g0 = mfma16x16x32(a0, bh00, g0); g0 = mfma16x16x32(a1, bh01, g0);
      g1 = mfma16x16x32(a0, bh10, g1); g1 = mfma16x16x32(a1, bh11, g1);
      g2 = mfma16x16x32(a0, bw00, g2); g2 = mfma16x16x32(a1, bw01, g2);
      g3 = mfma16x16x32(a0, bw10, g3); g3 = mfma16x16x32(a1, bw11, g3);
      #pragma unroll
      for (int e = 0; e < 4; ++e) {
        const int row = mt * 16 + hi * 4 + e;
        Gh[row * 36 + lr]      = __float2bfloat16(g0[e]);
        Gh[row * 36 + 16 + lr] = __float2bfloat16(g1[e]);
        Gw[row * 36 + lr]      = __float2bfloat16(g2[e]);
        Gw[row * 36 + 16 + lr] = __float2bfloat16(g3[e]);
      }
    }
  }
  __syncthreads();
  // ---- phase B: gather G -> regs ----
  bf16 ghr[11], gwr[11];
  #pragma unroll
  for (int t = 0; t < 11; ++t) {
    const int i = tid + t * 256;
    if (i < 196 * 14) {
      const int q = i / 14, kk = i - (i / 14) * 14;
      const int rh = q / 14 - kk + 13;
      const int rw2 = q - (q / 14) * 14 - kk + 13;
      ghr[t] = Gh[q * 36 + rh];
      gwr[t] = Gw[q * 36 + rw2];
    }
  }
  __syncthreads();
  // ---- phase C: write rel tables; stage K (swizzled gload_lds); stage V^T ----
  #pragma unroll
  for (int t = 0; t < 11; ++t) {
    const int i = tid + t * 256;
    if (i < 196 * 14) { relh_s[i] = ghr[t]; relw_s[i] = gwr[t]; }
  }
  for (int c = wv; c < 25; c += 4) {          // 25 calls x 1024 B = 200 K-rows
    const int row = c * 8 + (lane >> 3);
    const int ch  = (lane & 7) ^ (row & 7);   // pre-swizzled global source
    gload_lds16(Kp + row * 64 + ch * 8, klds + c * 1024);
  }
  for (int i = tid; i < 196 * 8; i += 256) {  // V^T staging (vectorized read)
    const int key = i >> 3, dg = (i & 7) * 8;
    const short8 v = *(const short8*)&Vp[key * 64 + dg];
    #pragma unroll
    for (int j = 0; j < 8; ++j) {
      const int idx = (dg + j) * 448 + key * 2;
      *(bf16*)(vtb + (idx ^ (j << 4))) = ((const bf16*)&v)[j];
    }
  }
  for (int i = tid; i < 64 * 28; i += 256) {  // zero-pad keys 196..223
    const int d = i / 28, key = 196 + i - (i / 28) * 28;
    const int idx = d * 448 + key * 2;
    *(bf16*)(vtb + (idx ^ ((d & 7) << 4))) = __float2bfloat16(0.f);
  }
  __syncthreads();

  // ---- main loop over q-tiles ----
  for (int qt = wv; qt < 13; qt += 4) {
    const int q = qt * 16 + lr;               // this lane's q-row
    const int qc = q < 196 ? q : 195;
    const short8 bq0 = *(const short8*)&Q[(qt * 16 + lr) * 64 + hi * 8];
    const short8 bq1 = *(const short8*)&Q[(qt * 16 + lr) * 64 + 32 + hi * 8];
    // S^T = K . Q^T  (13 key tiles of 16)
    f32x4 s[13];
    #pragma unroll
    for (int nt = 0; nt < 13; ++nt) {
      const int key = nt * 16 + lr;
      const char* kr = klds + key * 128;
      const short8 ka0 = *(const short8*)(kr + (((hi) ^ (key & 7)) << 4));
      const short8 ka1 = *(const short8*)(kr + (((hi + 4) ^ (key & 7)) << 4));
      f32x4 z = {};
      z = mfma16x16x32(ka0, bq0, z);
      z = mfma16x16x32(ka1, bq1, z);
      s[nt] = z;      // s[nt][e] = S[q=lr][key = nt*16 + hi*4 + e]
    }
    // bias + mask + softmax (per-lane row; cross-lane over {lr,lr+16,lr+32,lr+48})
    float mx = -3.0e38f;
    #pragma unroll
    for (int nt = 0; nt < 13; ++nt) {
      #pragma unroll
      for (int e = 0; e < 4; ++e) {
        const int key = nt * 16 + hi * 4 + e;
        const int kh = key / 14, kw = key - kh * 14;
        float v = s[nt][e] * 0.125f + __bfloat162float(relh_s[qc * 14 + kh])
                                    + __bfloat162float(relw_s[qc * 14 + kw]);
        v = (key < 196) ? v : -3.0e38f;
        s[nt][e] = v;
        mx = fmaxf(mx, v);
      }
    }
    mx = fmaxf(mx, __shfl_xor(mx, 16));
    mx = fmaxf(mx, __shfl_xor(mx, 32));
    float sm = 0.f;
    #pragma unroll
    for (int nt = 0; nt < 13; ++nt)
      #pragma unroll
      for (int e = 0; e < 4; ++e) {
        const float p = __expf(s[nt][e] - mx);
        s[nt][e] = p; sm += p;
      }
    sm += __shfl_xor(sm, 16);
    sm += __shfl_xor(sm, 32);
    const float rinv = 1.f / sm;
    // O^T = V^T . P^T  (7 key chunks of 32); P frag built in-register
    f32x4 o[4] = {};
    #pragma unroll
    for (int kk = 0; kk < 7; ++kk) {
      const uint32_t x0 = cvtpk(s[2 * kk][0] * rinv, s[2 * kk][1] * rinv);
      const uint32_t x1 = cvtpk(s[2 * kk][2] * rinv, s[2 * kk][3] * rinv);
      const uint32_t y0 = cvtpk(s[2 * kk + 1][0] * rinv, s[2 * kk + 1][1] * rinv);
      const uint32_t y1 = cvtpk(s[2 * kk + 1][2] * rinv, s[2 * kk + 1][3] * rinv);
      // round 1: xor 32 (hi-group g <-> g^2), send y for g<2 else x
      const uint32_t s0 = (hi < 2) ? y0 : x0, s1 = (hi < 2) ? y1 : x1;
      const uint32_t t0 = __shfl_xor(s0, 32), t1 = __shfl_xor(s1, 32);
      // round 2: xor 16; g∈{1,2} send own, g∈{0,3} send t
      const uint32_t o0 = (hi < 2) ? x0 : y0, o1 = (hi < 2) ? x1 : y1;
      const bool sendOwn = (hi == 1) || (hi == 2);
      const uint32_t u0 = sendOwn ? o0 : t0, u1 = sendOwn ? o1 : t1;
      const uint32_t r0 = __shfl_xor(u0, 16), r1 = __shfl_xor(u1, 16);
      // assemble frag: [first(2dw), second(2dw)]
      union { uint32_t u[4]; short8 v; } pf;
      pf.u[0] = (hi == 0) ? x0 : ((hi == 2) ? t0 : r0);
      pf.u[1] = (hi == 0) ? x1 : ((hi == 2) ? t1 : r1);
      pf.u[2] = (hi == 3) ? y0 : ((hi == 1) ? t0 : r0);
      pf.u[3] = (hi == 3) ? y1 : ((hi == 1) ? t1 : r1);
      #pragma unroll
      for (int n2 = 0; n2 < 4; ++n2) {
        const int d = n2 * 16 + lr;
        const int idx = d * 448 + (kk * 32 + hi * 8) * 2;
        const short8 va = *(const short8*)(vtb + (idx ^ ((lr & 7) << 4)));
        o[n2] = mfma16x16x32(va, pf.v, o[n2]);   // o[n2][e] = O[q][d=n2*16+hi*4+e]
      }
    }
    // store O rows (dense 8B per lane, aout[head][MPAD][64])
    if (q < 196) {
      bf16* orow = aout + ((size_t)head * MPAD + win * 196 + q) * 64;
      #pragma unroll
      for (int n2 = 0; n2 < 4; ++n2) {
        uint32_t d0 = cvtpk(o[n2][0], o[n2][1]);
        uint32_t d1 = cvtpk(o[n2][2], o[n2][3]);
        uint32_t* dst = (uint32_t*)&orow[n2 * 16 + hi * 4];
        dst[0] = d0; dst[1] = d1;
      }
    }
  }
}

// ---------------- host ----------------
extern "C" void kernel_launch(void* const* d_in, const int* in_sizes, int n_in,
                              void* d_out, int out_size, void* d_ws, size_t ws_size,
                              hipStream_t stream) {
  (void)in_sizes; (void)n_in; (void)out_size; (void)ws_size;
  const float* x      = (const float*)d_in[0];
  const float* ln1_g  = (const float*)d_in[1];
  const float* ln1_b  = (const float*)d_in[2];
  const float* qkv_w  = (const float*)d_in[3];
  const float* qkv_b  = (const float*)d_in[4];
  const float* proj_w = (const float*)d_in[5];
  const float* proj_b = (const float*)d_in[6];
  const float* rph    = (const float*)d_in[7];
  const float* rpw    = (const float*)d_in[8];
  const float* ln2_g  = (const float*)d_in[9];
  const float* ln2_b  = (const float*)d_in[10];
  const float* w1     = (const float*)d_in[11];
  const float* b1v    = (const float*)d_in[12];
  const float* w2     = (const float*)d_in[13];
  const float* b2v    = (const float*)d_in[14];
  float* outp = (float*)d_out;   // also serves as x1 (written by proj epilogue)

  // -------- workspace layout with liveness-based aliasing (~276 MB) --------
  char* ws = (char*)d_ws;
  size_t off = 0;
  auto alloc = [&](size_t bytes) { char* p = ws + off; off += (bytes + 255) & ~(size_t)255; return p; };
  bf16* qkv_wt  = (bf16*)alloc((size_t)2304 * 768 * 2);
  bf16* proj_wt = (bf16*)alloc((size_t)768 * 768 * 2);
  bf16* w1t     = (bf16*)alloc((size_t)3072 * 768 * 2);
  bf16* w2t     = (bf16*)alloc((size_t)768 * 3072 * 2);
  // region B: xnwin (qkv phase) -> attnout [12][MPAD][64] (proj) -> xn2 (mlp)
  const size_t szB1 = (size_t)MPAD * 768 * 2;
  const size_t szB2 = (size_t)TOK2 * 768 * 2;
  char* regB = alloc(szB1 > szB2 ? szB1 : szB2);
  // region C: q/k/v (attn phase) -> hbuf (mlp phase)
  const size_t szQKV = (size_t)3 * 2400 * NPR * 64 * 2;
  const size_t szH   = (size_t)TOK2 * 3072 * 2;
  char* regC = alloc(szQKV > szH ? szQKV : szH);

  bf16* xnwin   = (bf16*)regB;
  bf16* attnout = (bf16*)regB;
  bf16* xn2     = (bf16*)regB;
  bf16* qbuf    = (bf16*)regC;
  bf16* kbuf    = qbuf + (size_t)2400 * NPR * 64;
  bf16* vbuf    = kbuf + (size_t)2400 * NPR * 64;
  bf16* hbuf    = (bf16*)regC;

  // weights -> bf16 transposed [N][K]
  transpose_cast<<<dim3(2304 / 32, 768 / 32), 256, 0, stream>>>(qkv_w, qkv_wt, 768, 2304);
  transpose_cast<<<dim3(768 / 32, 768 / 32), 256, 0, stream>>>(proj_w, proj_wt, 768, 768);
  transpose_cast<<<dim3(3072 / 32, 768 / 32), 256, 0, stream>>>(w1, w1t, 768, 3072);
  transpose_cast<<<dim3(768 / 32, 3072 / 32), 256, 0, stream>>>(w2, w2t, 3072, 768);

  // LN1 + window partition
  ln1_partition<<<dim3(MROWS / 4), 256, 0, stream>>>(x, ln1_g, ln1_b, xnwin);

  // qkv GEMM [39296 x 2304] = xnwin @ qkv_w, scatter to q/k/v
  gemm_bf16<0><<<dim3(2304 / 128, MPAD / 128), 256, 0, stream>>>(
      xnwin, qkv_wt, qkv_b, 768, MROWS, nullptr, nullptr, qbuf, kbuf, vbuf);

  // attention (writes attnout = regB; xnwin dead now)
  attn_kernel<<<dim3(2400), 256, 0, stream>>>(qbuf, kbuf, vbuf, rph, rpw, attnout);

  // proj GEMM + unpartition + residual -> x1 (= outp, f32)
  gemm_bf16<1><<<dim3(768 / 128, MPAD / 128), 256, 0, stream>>>(
      attnout, proj_wt, proj_b, 768, MROWS, x, outp, nullptr, nullptr, nullptr);

  // LN2 (writes xn2, aliases attnout -- dead now)
  ln2_kernel<<<dim3(TOK2 / 4), 256, 0, stream>>>(outp, ln2_g, ln2_b, xn2);

  // MLP (hbuf aliases q/k/v -- dead now)
  gemm_bf16<2><<<dim3(3072 / 128, TOK2 / 128), 256, 0, stream>>>(
      xn2, w1t, b1v, 768, TOK2, nullptr, nullptr, hbuf, nullptr, nullptr);
  gemm_bf16<3><<<dim3(768 / 128, TOK2 / 128), 256, 0, stream>>>(
      hbuf, w2t, b2v, 3072, TOK2, outp, outp, nullptr, nullptr, nullptr);
}

// Round 5
// 1292.027 us; speedup vs baseline: 1.3604x; 1.0986x over previous
//
#include <hip/hip_runtime.h>
#include <hip/hip_bf16.h>
#include <cstdint>
#include <cstddef>

using bf16 = __hip_bfloat16;
typedef __attribute__((ext_vector_type(8))) short short8;
typedef __attribute__((ext_vector_type(4))) float f32x4;

typedef __attribute__((address_space(1))) const void as1_void;
typedef __attribute__((address_space(3))) void as3_void;

__device__ __forceinline__ f32x4 mfma16x16x32(short8 a, short8 b, f32x4 c) {
  return __builtin_amdgcn_mfma_f32_16x16x32_bf16(a, b, c, 0, 0, 0);
}

__device__ __forceinline__ void gload_lds16(const void* g, void* l) {
  __builtin_amdgcn_global_load_lds((as1_void*)g, (as3_void*)l, 16, 0, 0);
}

__device__ __forceinline__ uint32_t cvtpk(float a, float b) {
  uint32_t r;
  asm("v_cvt_pk_bf16_f32 %0, %1, %2" : "=v"(r) : "v"(a), "v"(b));
  return r;
}

// ---------------- problem constants ----------------
// B=8, H=W=64, C=768, NH=12, HD=64, WS=14 -> Hp=Wp=70, 5x5 windows, Bn=200
// N=196 tokens/window, padded rows NPR=208, padded keys NPK=224 (7x32)

static constexpr int MROWS = 39200;
static constexpr int MPAD  = 39296;
static constexpr int TOK2  = 32768;
static constexpr int NPR   = 208;

// ---------------- weight transpose+cast:  in f32 [K][N] -> out bf16 [N][K] ----
__global__ __launch_bounds__(256)
void transpose_cast(const float* __restrict__ in, bf16* __restrict__ out, int K, int N) {
  __shared__ float t[32][33];
  const int tx = threadIdx.x & 31, ty = threadIdx.x >> 5;
  const int bx = blockIdx.x, by = blockIdx.y;   // bx: N-tile, by: K-tile
  const int x = bx * 32 + tx;
  for (int r = ty; r < 32; r += 8)
    t[r][tx] = in[(size_t)(by * 32 + r) * N + x];
  __syncthreads();
  const int xo = by * 32 + tx;
  for (int r = ty; r < 32; r += 8)
    out[(size_t)(bx * 32 + r) * K + xo] = __float2bfloat16(t[tx][r]);
}

// ---------------- LN1 + window partition -> bf16 [MPAD][768] ----------------
__global__ __launch_bounds__(256)
void ln1_partition(const float* __restrict__ x, const float* __restrict__ g,
                   const float* __restrict__ bb, bf16* __restrict__ out) {
  const int token = blockIdx.x * 4 + (threadIdx.x >> 6);  // < 39200
  const int lane = threadIdx.x & 63;
  const int win = token / 196, tok = token % 196;
  const int b_ = win / 25, wh = (win / 5) % 5, ww = win % 5;
  const int i = tok / 14, j = tok % 14;
  const int h = wh * 14 + i, w = ww * 14 + j;
  bf16* o = out + (size_t)token * 768;
  if (h >= 64 || w >= 64) {
    for (int t = 0; t < 12; ++t) o[lane + 64 * t] = __float2bfloat16(0.f);
    return;
  }
  const float* src = x + ((size_t)((b_ * 64 + h) * 64 + w)) * 768;
  float vals[12], s = 0.f, ss = 0.f;
  #pragma unroll
  for (int t = 0; t < 12; ++t) {
    float v = src[lane + 64 * t];
    vals[t] = v; s += v; ss += v * v;
  }
  #pragma unroll
  for (int d = 32; d > 0; d >>= 1) { s += __shfl_xor(s, d); ss += __shfl_xor(ss, d); }
  const float mu = s * (1.f / 768.f);
  const float var = ss * (1.f / 768.f) - mu * mu;
  const float inv = rsqrtf(var + 1e-6f);
  #pragma unroll
  for (int t = 0; t < 12; ++t) {
    const int c = lane + 64 * t;
    o[c] = __float2bfloat16((vals[t] - mu) * inv * g[c] + bb[c]);
  }
}

// ---------------- LN2 on x1 (f32, dense [32768][768]) -> bf16 ----------------
__global__ __launch_bounds__(256)
void ln2_kernel(const float* __restrict__ x1, const float* __restrict__ g,
                const float* __restrict__ bb, bf16* __restrict__ out) {
  const int token = blockIdx.x * 4 + (threadIdx.x >> 6);  // < 32768
  const int lane = threadIdx.x & 63;
  const float* src = x1 + (size_t)token * 768;
  bf16* o = out + (size_t)token * 768;
  float vals[12], s = 0.f, ss = 0.f;
  #pragma unroll
  for (int t = 0; t < 12; ++t) {
    float v = src[lane + 64 * t];
    vals[t] = v; s += v; ss += v * v;
  }
  #pragma unroll
  for (int d = 32; d > 0; d >>= 1) { s += __shfl_xor(s, d); ss += __shfl_xor(ss, d); }
  const float mu = s * (1.f / 768.f);
  const float var = ss * (1.f / 768.f) - mu * mu;
  const float inv = rsqrtf(var + 1e-6f);
  #pragma unroll
  for (int t = 0; t < 12; ++t) {
    const int c = lane + 64 * t;
    o[c] = __float2bfloat16((vals[t] - mu) * inv * g[c] + bb[c]);
  }
}

// ---------------- generic bf16 GEMM, 128x128 tile, BK=32, 2-phase dbuf ------
// EPI 0: qkv scatter; EPI 1: proj (A in [head][MPAD][64] layout) + residual;
// EPI 2: gelu -> bf16; EPI 3: dense residual add.
// K-steps must be EVEN (K % 64 == 0): true for 768 and 3072.
template<int EPI>
__global__ __launch_bounds__(256)
void gemm_bf16(const bf16* __restrict__ A, const bf16* __restrict__ Bt,
               const float* __restrict__ bias, int K, int Mreal,
               const float* __restrict__ fin, float* __restrict__ fout,
               bf16* __restrict__ ob0, bf16* __restrict__ ob1, bf16* __restrict__ ob2) {
  __shared__ __align__(16) bf16 lA[2][128 * 32];
  __shared__ __align__(16) bf16 lB[2][128 * 32];
  const int tid = threadIdx.x;
  const int lane = tid & 63, wv = tid >> 6;
  const int lr = lane & 15, hi = lane >> 4;
  const int wm = wv >> 1, wn = wv & 1;
  const size_t arow0 = (size_t)blockIdx.y * 128;
  const size_t brow0 = (size_t)blockIdx.x * 128;
  f32x4 acc[4][4] = {};

  auto stage = [&](int buf, int kt) {
    const int k0 = kt * 32;
    #pragma unroll
    for (int it = 0; it < 2; ++it) {
      const int seg = it * 256 + tid;
      const int row = seg >> 2, kq = seg & 3;
      const size_t dst = (size_t)(it * 256 + wv * 64) * 8;
      if constexpr (EPI == 1) {
        const int k = k0 + kq * 8;   // A layout: [head][MPAD][64]
        gload_lds16(A + ((size_t)(k >> 6) * MPAD + arow0 + row) * 64 + (k & 63), &lA[buf][dst]);
      } else {
        gload_lds16(A + (arow0 + row) * K + k0 + kq * 8, &lA[buf][dst]);
      }
      gload_lds16(Bt + (brow0 + row) * K + k0 + kq * 8, &lB[buf][dst]);
    }
  };
  auto compute = [&](int buf) {
    short8 af[4], bfr[4];
    #pragma unroll
    for (int m = 0; m < 4; ++m) af[m] = *(const short8*)&lA[buf][(wm * 64 + m * 16 + lr) * 32 + hi * 8];
    #pragma unroll
    for (int n = 0; n < 4; ++n) bfr[n] = *(const short8*)&lB[buf][(wn * 64 + n * 16 + lr) * 32 + hi * 8];
    #pragma unroll
    for (int m = 0; m < 4; ++m)
      #pragma unroll
      for (int n = 0; n < 4; ++n)
        acc[m][n] = mfma16x16x32(af[m], bfr[n], acc[m][n]);
  };

  const int nt = K >> 5;               // even
  stage(0, 0);
  __syncthreads();                     // drains vmcnt(0): tile 0 staged
  for (int t = 0; t < nt; t += 2) {
    if (t + 1 < nt) stage(1, t + 1);   // issue next-tile loads (overlap w/ MFMA)
    compute(0);
    __syncthreads();                   // vmcnt(0): tile t+1 landed; buf0 free
    if (t + 2 < nt) stage(0, t + 2);
    compute(1);
    __syncthreads();
  }

  // epilogue
  #pragma unroll
  for (int n = 0; n < 4; ++n) {
    const int col = (int)brow0 + wn * 64 + n * 16 + lr;
    const float bv = bias[col];
    #pragma unroll
    for (int m = 0; m < 4; ++m) {
      #pragma unroll
      for (int e = 0; e < 4; ++e) {
        const int row = (int)arow0 + wm * 64 + m * 16 + hi * 4 + e;
        const float v = acc[m][n][e] + bv;
        if constexpr (EPI == 0) {
          if (row < Mreal) {
            const int win = row / 196, tok = row % 196;
            const int which = col / 768, head = (col >> 6) % 12, d = col & 63;
            bf16* dst = (which == 0) ? ob0 : ((which == 1) ? ob1 : ob2);
            dst[((size_t)(win * 12 + head) * NPR + tok) * 64 + d] = __float2bfloat16(v);
          }
        } else if constexpr (EPI == 1) {
          if (row < Mreal) {
            const int win = row / 196, tok = row % 196;
            const int b_ = win / 25, wh = (win / 5) % 5, ww = win % 5;
            const int i = tok / 14, j = tok % 14;
            const int h = wh * 14 + i, w = ww * 14 + j;
            if (h < 64 && w < 64) {
              const size_t idx = ((size_t)((b_ * 64 + h) * 64 + w)) * 768 + col;
              fout[idx] = fin[idx] + v;
            }
          }
        } else if constexpr (EPI == 2) {
          const float gl = 0.5f * v * (1.f + erff(v * 0.70710678118f));
          ob0[(size_t)row * 3072 + col] = __float2bfloat16(gl);
        } else {
          const size_t idx = (size_t)row * 768 + col;
          fout[idx] = fin[idx] + v;
        }
      }
    }
  }
}

// ---------------- fused window attention, one block per (window, head) -------
// Swapped-operand design: S^T = mfma(K, Q) so each lane owns one q-row (q = lr).
// P stays in registers (cvt_pk + 2-round shfl exchange), PV computed as O^T.
// LDS (static, 65248 B):
//   phase A (aliased):  pbh[32][64] @0 | pbw @4096 | Gh[208][36] @8192 | Gw @23168
//   main:   klds[200][64] swz @0 | vt[64][224] swz @25600 | relh @54272 | relw @59760
// out layout: aout[head][MPAD][64]
__global__ __launch_bounds__(256)
void attn_kernel(const bf16* __restrict__ qb, const bf16* __restrict__ kb,
                 const bf16* __restrict__ vb, const float* __restrict__ rph,
                 const float* __restrict__ rpw, bf16* __restrict__ aout) {
  __shared__ __align__(16) char SM[65248];
  bf16* pbh    = (bf16*)SM;
  bf16* pbw    = (bf16*)(SM + 4096);
  bf16* Gh     = (bf16*)(SM + 8192);
  bf16* Gw     = (bf16*)(SM + 23168);
  char* klds   = SM;                    // [200 rows][128 B], XOR-swizzled
  char* vtb    = SM + 25600;            // [64 d][448 B], XOR-swizzled
  bf16* relh_s = (bf16*)(SM + 54272);   // [196][14]
  bf16* relw_s = (bf16*)(SM + 59760);   // [196][14]

  const int bh = blockIdx.x;             // 0..2399
  const int win = bh / 12, head = bh % 12;
  const bf16* Q  = qb + (size_t)bh * NPR * 64;
  const bf16* Kp = kb + (size_t)bh * NPR * 64;
  const bf16* Vp = vb + (size_t)bh * NPR * 64;
  const int tid = threadIdx.x, lane = tid & 63, wv = tid >> 6;
  const int lr = lane & 15, hi = lane >> 4;

  // ---- phase A0: stage rel_pos tables (bf16, zero-padded to 32 rows) ----
  for (int i = tid; i < 32 * 64; i += 256) {
    const int r = i >> 6, c = i & 63;
    const bool ok = r < 27;
    pbh[i] = __float2bfloat16(ok ? rph[r * 64 + c] : 0.f);
    pbw[i] = __float2bfloat16(ok ? rpw[r * 64 + c] : 0.f);
  }
  __syncthreads();
  // ---- phase A: G = Q @ relpos^T via MFMA ----
  {
    short8 bh00 = *(const short8*)&pbh[(lr) * 64 + hi * 8];
    short8 bh01 = *(const short8*)&pbh[(lr) * 64 + 32 + hi * 8];
    short8 bh10 = *(const short8*)&pbh[(16 + lr) * 64 + hi * 8];
    short8 bh11 = *(const short8*)&pbh[(16 + lr) * 64 + 32 + hi * 8];
    short8 bw00 = *(const short8*)&pbw[(lr) * 64 + hi * 8];
    short8 bw01 = *(const short8*)&pbw[(lr) * 64 + 32 + hi * 8];
    short8 bw10 = *(const short8*)&pbw[(16 + lr) * 64 + hi * 8];
    short8 bw11 = *(const short8*)&pbw[(16 + lr) * 64 + 32 + hi * 8];
    for (int mt = wv; mt < 13; mt += 4) {
      const short8 a0 = *(const short8*)&Q[(mt * 16 + lr) * 64 + hi * 8];
      const short8 a1 = *(const short8*)&Q[(mt * 16 + lr) * 64 + 32 + hi * 8];
      f32x4 g0 = {}, g1 = {}, g2 = {}, g3 = {};
      g0 = mfma16x16x32(a0, bh00, g0); g0 = mfma16x16x32(a1, bh01, g0);
      g1 = mfma16x16x32(a0, bh10, g1); g1 = mfma16x16x32(a1, bh11, g1);
      g2 = mfma16x16x32(a0, bw00, g2); g2 = mfma16x16x32(a1, bw01, g2);
      g3 = mfma16x16x32(a0, bw10, g3); g3 = mfma16x16x32(a1, bw11, g3);
      #pragma unroll
      for (int e = 0; e < 4; ++e) {
        const int row = mt * 16 + hi * 4 + e;
        Gh[row * 36 + lr]      = __float2bfloat16(g0[e]);
        Gh[row * 36 + 16 + lr] = __float2bfloat16(g1[e]);
        Gw[row * 36 + lr]      = __float2bfloat16(g2[e]);
        Gw[row * 36 + 16 + lr] = __float2bfloat16(g3[e]);
      }
    }
  }
  __syncthreads();
  // ---- phase B: gather G -> regs ----
  bf16 ghr[11], gwr[11];
  #pragma unroll
  for (int t = 0; t < 11; ++t) {
    const int i = tid + t * 256;
    if (i < 196 * 14) {
      const int q = i / 14, kk = i - (i / 14) * 14;
      const int rh = q / 14 - kk + 13;
      const int rw2 = q - (q / 14) * 14 - kk + 13;
      ghr[t] = Gh[q * 36 + rh];
      gwr[t] = Gw[q * 36 + rw2];
    }
  }
  __syncthreads();
  // ---- phase C: write rel tables; stage K (swizzled gload_lds); stage V^T ----
  #pragma unroll
  for (int t = 0; t < 11; ++t) {
    const int i = tid + t * 256;
    if (i < 196 * 14) { relh_s[i] = ghr[t]; relw_s[i] = gwr[t]; }
  }
  for (int c = wv; c < 25; c += 4) {          // 25 calls x 1024 B = 200 K-rows
    const int row = c * 8 + (lane >> 3);
    const int ch  = (lane & 7) ^ (row & 7);   // pre-swizzled global source
    gload_lds16(Kp + row * 64 + ch * 8, klds + c * 1024);
  }
  for (int i = tid; i < 196 * 8; i += 256) {  // V^T staging (vectorized read)
    const int key = i >> 3, dg = (i & 7) * 8;
    const short8 v = *(const short8*)&Vp[key * 64 + dg];
    #pragma unroll
    for (int j = 0; j < 8; ++j) {
      const int idx = (dg + j) * 448 + key * 2;
      *(bf16*)(vtb + (idx ^ (j << 4))) = ((const bf16*)&v)[j];
    }
  }
  for (int i = tid; i < 64 * 28; i += 256) {  // zero-pad keys 196..223
    const int d = i / 28, key = 196 + i - (i / 28) * 28;
    const int idx = d * 448 + key * 2;
    *(bf16*)(vtb + (idx ^ ((d & 7) << 4))) = __float2bfloat16(0.f);
  }
  __syncthreads();

  // ---- main loop over q-tiles ----
  for (int qt = wv; qt < 13; qt += 4) {
    const int q = qt * 16 + lr;               // this lane's q-row
    const int qc = q < 196 ? q : 195;
    const short8 bq0 = *(const short8*)&Q[(qt * 16 + lr) * 64 + hi * 8];
    const short8 bq1 = *(const short8*)&Q[(qt * 16 + lr) * 64 + 32 + hi * 8];
    // S^T = K . Q^T  (13 key tiles of 16)
    f32x4 s[13];
    __builtin_amdgcn_s_setprio(1);
    #pragma unroll
    for (int nt = 0; nt < 13; ++nt) {
      const int key = nt * 16 + lr;
      const char* kr = klds + key * 128;
      const short8 ka0 = *(const short8*)(kr + (((hi) ^ (key & 7)) << 4));
      const short8 ka1 = *(const short8*)(kr + (((hi + 4) ^ (key & 7)) << 4));
      f32x4 z = {};
      z = mfma16x16x32(ka0, bq0, z);
      z = mfma16x16x32(ka1, bq1, z);
      s[nt] = z;      // s[nt][e] = S[q=lr][key = nt*16 + hi*4 + e]
    }
    __builtin_amdgcn_s_setprio(0);
    // bias + mask + softmax (per-lane row; cross-lane over {lr,lr+16,lr+32,lr+48})
    float mx = -3.0e38f;
    #pragma unroll
    for (int nt = 0; nt < 13; ++nt) {
      #pragma unroll
      for (int e = 0; e < 4; ++e) {
        const int key = nt * 16 + hi * 4 + e;
        const int kh = key / 14, kw = key - kh * 14;
        float v = s[nt][e] * 0.125f + __bfloat162float(relh_s[qc * 14 + kh])
                                    + __bfloat162float(relw_s[qc * 14 + kw]);
        v = (key < 196) ? v : -3.0e38f;
        s[nt][e] = v;
        mx = fmaxf(mx, v);
      }
    }
    mx = fmaxf(mx, __shfl_xor(mx, 16));
    mx = fmaxf(mx, __shfl_xor(mx, 32));
    float sm = 0.f;
    #pragma unroll
    for (int nt = 0; nt < 13; ++nt)
      #pragma unroll
      for (int e = 0; e < 4; ++e) {
        const float p = __expf(s[nt][e] - mx);
        s[nt][e] = p; sm += p;
      }
    sm += __shfl_xor(sm, 16);
    sm += __shfl_xor(sm, 32);
    const float rinv = 1.f / sm;
    // O^T = V^T . P^T  (7 key chunks of 32); P frag built in-register
    f32x4 o[4] = {};
    #pragma unroll
    for (int kk = 0; kk < 7; ++kk) {
      const uint32_t x0 = cvtpk(s[2 * kk][0] * rinv, s[2 * kk][1] * rinv);
      const uint32_t x1 = cvtpk(s[2 * kk][2] * rinv, s[2 * kk][3] * rinv);
      const uint32_t y0 = cvtpk(s[2 * kk + 1][0] * rinv, s[2 * kk + 1][1] * rinv);
      const uint32_t y1 = cvtpk(s[2 * kk + 1][2] * rinv, s[2 * kk + 1][3] * rinv);
      // round 1: xor 32 (hi-group g <-> g^2), send y for g<2 else x
      const uint32_t s0 = (hi < 2) ? y0 : x0, s1 = (hi < 2) ? y1 : x1;
      const uint32_t t0 = __shfl_xor(s0, 32), t1 = __shfl_xor(s1, 32);
      // round 2: xor 16; g∈{1,2} send own, g∈{0,3} send t
      const uint32_t o0 = (hi < 2) ? x0 : y0, o1 = (hi < 2) ? x1 : y1;
      const bool sendOwn = (hi == 1) || (hi == 2);
      const uint32_t u0 = sendOwn ? o0 : t0, u1 = sendOwn ? o1 : t1;
      const uint32_t r0 = __shfl_xor(u0, 16), r1 = __shfl_xor(u1, 16);
      // assemble frag: [first(2dw), second(2dw)]
      union { uint32_t u[4]; short8 v; } pf;
      pf.u[0] = (hi == 0) ? x0 : ((hi == 2) ? t0 : r0);
      pf.u[1] = (hi == 0) ? x1 : ((hi == 2) ? t1 : r1);
      pf.u[2] = (hi == 3) ? y0 : ((hi == 1) ? t0 : r0);
      pf.u[3] = (hi == 3) ? y1 : ((hi == 1) ? t1 : r1);
      __builtin_amdgcn_s_setprio(1);
      #pragma unroll
      for (int n2 = 0; n2 < 4; ++n2) {
        const int d = n2 * 16 + lr;
        const int idx = d * 448 + (kk * 32 + hi * 8) * 2;
        const short8 va = *(const short8*)(vtb + (idx ^ ((lr & 7) << 4)));
        o[n2] = mfma16x16x32(va, pf.v, o[n2]);   // o[n2][e] = O[q][d=n2*16+hi*4+e]
      }
      __builtin_amdgcn_s_setprio(0);
    }
    // store O rows (dense 8B per lane, aout[head][MPAD][64])
    if (q < 196) {
      bf16* orow = aout + ((size_t)head * MPAD + win * 196 + q) * 64;
      #pragma unroll
      for (int n2 = 0; n2 < 4; ++n2) {
        uint32_t d0 = cvtpk(o[n2][0], o[n2][1]);
        uint32_t d1 = cvtpk(o[n2][2], o[n2][3]);
        uint32_t* dst = (uint32_t*)&orow[n2 * 16 + hi * 4];
        dst[0] = d0; dst[1] = d1;
      }
    }
  }
}

// ---------------- host ----------------
extern "C" void kernel_launch(void* const* d_in, const int* in_sizes, int n_in,
                              void* d_out, int out_size, void* d_ws, size_t ws_size,
                              hipStream_t stream) {
  (void)in_sizes; (void)n_in; (void)out_size; (void)ws_size;
  const float* x      = (const float*)d_in[0];
  const float* ln1_g  = (const float*)d_in[1];
  const float* ln1_b  = (const float*)d_in[2];
  const float* qkv_w  = (const float*)d_in[3];
  const float* qkv_b  = (const float*)d_in[4];
  const float* proj_w = (const float*)d_in[5];
  const float* proj_b = (const float*)d_in[6];
  const float* rph    = (const float*)d_in[7];
  const float* rpw    = (const float*)d_in[8];
  const float* ln2_g  = (const float*)d_in[9];
  const float* ln2_b  = (const float*)d_in[10];
  const float* w1     = (const float*)d_in[11];
  const float* b1v    = (const float*)d_in[12];
  const float* w2     = (const float*)d_in[13];
  const float* b2v    = (const float*)d_in[14];
  float* outp = (float*)d_out;   // also serves as x1 (written by proj epilogue)

  // -------- workspace layout with liveness-based aliasing (~276 MB) --------
  char* ws = (char*)d_ws;
  size_t off = 0;
  auto alloc = [&](size_t bytes) { char* p = ws + off; off += (bytes + 255) & ~(size_t)255; return p; };
  bf16* qkv_wt  = (bf16*)alloc((size_t)2304 * 768 * 2);
  bf16* proj_wt = (bf16*)alloc((size_t)768 * 768 * 2);
  bf16* w1t     = (bf16*)alloc((size_t)3072 * 768 * 2);
  bf16* w2t     = (bf16*)alloc((size_t)768 * 3072 * 2);
  // region B: xnwin (qkv phase) -> attnout [12][MPAD][64] (proj) -> xn2 (mlp)
  const size_t szB1 = (size_t)MPAD * 768 * 2;
  const size_t szB2 = (size_t)TOK2 * 768 * 2;
  char* regB = alloc(szB1 > szB2 ? szB1 : szB2);
  // region C: q/k/v (attn phase) -> hbuf (mlp phase)
  const size_t szQKV = (size_t)3 * 2400 * NPR * 64 * 2;
  const size_t szH   = (size_t)TOK2 * 3072 * 2;
  char* regC = alloc(szQKV > szH ? szQKV : szH);

  bf16* xnwin   = (bf16*)regB;
  bf16* attnout = (bf16*)regB;
  bf16* xn2     = (bf16*)regB;
  bf16* qbuf    = (bf16*)regC;
  bf16* kbuf    = qbuf + (size_t)2400 * NPR * 64;
  bf16* vbuf    = kbuf + (size_t)2400 * NPR * 64;
  bf16* hbuf    = (bf16*)regC;

  // weights -> bf16 transposed [N][K]
  transpose_cast<<<dim3(2304 / 32, 768 / 32), 256, 0, stream>>>(qkv_w, qkv_wt, 768, 2304);
  transpose_cast<<<dim3(768 / 32, 768 / 32), 256, 0, stream>>>(proj_w, proj_wt, 768, 768);
  transpose_cast<<<dim3(3072 / 32, 768 / 32), 256, 0, stream>>>(w1, w1t, 768, 3072);
  transpose_cast<<<dim3(768 / 32, 3072 / 32), 256, 0, stream>>>(w2, w2t, 3072, 768);

  // LN1 + window partition
  ln1_partition<<<dim3(MROWS / 4), 256, 0, stream>>>(x, ln1_g, ln1_b, xnwin);

  // qkv GEMM [39296 x 2304] = xnwin @ qkv_w, scatter to q/k/v
  gemm_bf16<0><<<dim3(2304 / 128, MPAD / 128), 256, 0, stream>>>(
      xnwin, qkv_wt, qkv_b, 768, MROWS, nullptr, nullptr, qbuf, kbuf, vbuf);

  // attention (writes attnout = regB; xnwin dead now)
  attn_kernel<<<dim3(2400), 256, 0, stream>>>(qbuf, kbuf, vbuf, rph, rpw, attnout);

  // proj GEMM + unpartition + residual -> x1 (= outp, f32)
  gemm_bf16<1><<<dim3(768 / 128, MPAD / 128), 256, 0, stream>>>(
      attnout, proj_wt, proj_b, 768, MROWS, x, outp, nullptr, nullptr, nullptr);

  // LN2 (writes xn2, aliases attnout -- dead now)
  ln2_kernel<<<dim3(TOK2 / 4), 256, 0, stream>>>(outp, ln2_g, ln2_b, xn2);

  // MLP (hbuf aliases q/k/v -- dead now)
  gemm_bf16<2><<<dim3(3072 / 128, TOK2 / 128), 256, 0, stream>>>(
      xn2, w1t, b1v, 768, TOK2, nullptr, nullptr, hbuf, nullptr, nullptr);
  gemm_bf16<3><<<dim3(768 / 128, TOK2 / 128), 256, 0, stream>>>(
      hbuf, w2t, b2v, 3072, TOK2, outp, outp, nullptr, nullptr, nullptr);
}

// Round 6
// 1134.793 us; speedup vs baseline: 1.5488x; 1.1386x over previous
//
#include <hip/hip_runtime.h>
#include <hip/hip_bf16.h>
#include <cstdint>
#include <cstddef>

using bf16 = __hip_bfloat16;
typedef __attribute__((ext_vector_type(8))) short short8;
typedef __attribute__((ext_vector_type(4))) float f32x4;

typedef __attribute__((address_space(1))) const void as1_void;
typedef __attribute__((address_space(3))) void as3_void;

__device__ __forceinline__ f32x4 mfma16x16x32(short8 a, short8 b, f32x4 c) {
  return __builtin_amdgcn_mfma_f32_16x16x32_bf16(a, b, c, 0, 0, 0);
}

__device__ __forceinline__ void gload_lds16(const void* g, void* l) {
  __builtin_amdgcn_global_load_lds((as1_void*)g, (as3_void*)l, 16, 0, 0);
}

__device__ __forceinline__ uint32_t cvtpk(float a, float b) {
  uint32_t r;
  asm("v_cvt_pk_bf16_f32 %0, %1, %2" : "=v"(r) : "v"(a), "v"(b));
  return r;
}

// ---------------- problem constants ----------------
// B=8, H=W=64, C=768, NH=12, HD=64, WS=14 -> Hp=Wp=70, 5x5 windows, Bn=200
// N=196 tokens/window; GEMM M = 39200, padded 39296; dense tokens = 32768

static constexpr int MROWS = 39200;
static constexpr int MPAD  = 39296;
static constexpr int TOK2  = 32768;

// ---------------- weight transpose+cast:  in f32 [K][N] -> out bf16 [N][K] ----
__global__ __launch_bounds__(256)
void transpose_cast(const float* __restrict__ in, bf16* __restrict__ out, int K, int N) {
  __shared__ float t[32][33];
  const int tx = threadIdx.x & 31, ty = threadIdx.x >> 5;
  const int bx = blockIdx.x, by = blockIdx.y;   // bx: N-tile, by: K-tile
  const int x = bx * 32 + tx;
  for (int r = ty; r < 32; r += 8)
    t[r][tx] = in[(size_t)(by * 32 + r) * N + x];
  __syncthreads();
  const int xo = by * 32 + tx;
  for (int r = ty; r < 32; r += 8)
    out[(size_t)(bx * 32 + r) * K + xo] = __float2bfloat16(t[tx][r]);
}

// ---------------- LN1 + window partition -> bf16 [MPAD][768] ----------------
__global__ __launch_bounds__(256)
void ln1_partition(const float* __restrict__ x, const float* __restrict__ g,
                   const float* __restrict__ bb, bf16* __restrict__ out) {
  const int token = blockIdx.x * 4 + (threadIdx.x >> 6);  // < 39200
  const int lane = threadIdx.x & 63;
  const int win = token / 196, tok = token % 196;
  const int b_ = win / 25, wh = (win / 5) % 5, ww = win % 5;
  const int i = tok / 14, j = tok % 14;
  const int h = wh * 14 + i, w = ww * 14 + j;
  bf16* o = out + (size_t)token * 768;
  if (h >= 64 || w >= 64) {
    for (int t = 0; t < 12; ++t) o[lane + 64 * t] = __float2bfloat16(0.f);
    return;
  }
  const float* src = x + ((size_t)((b_ * 64 + h) * 64 + w)) * 768;
  float vals[12], s = 0.f, ss = 0.f;
  #pragma unroll
  for (int t = 0; t < 12; ++t) {
    float v = src[lane + 64 * t];
    vals[t] = v; s += v; ss += v * v;
  }
  #pragma unroll
  for (int d = 32; d > 0; d >>= 1) { s += __shfl_xor(s, d); ss += __shfl_xor(ss, d); }
  const float mu = s * (1.f / 768.f);
  const float var = ss * (1.f / 768.f) - mu * mu;
  const float inv = rsqrtf(var + 1e-6f);
  #pragma unroll
  for (int t = 0; t < 12; ++t) {
    const int c = lane + 64 * t;
    o[c] = __float2bfloat16((vals[t] - mu) * inv * g[c] + bb[c]);
  }
}

// ---------------- LN2 on x1 (f32, dense [32768][768]) -> bf16 ----------------
__global__ __launch_bounds__(256)
void ln2_kernel(const float* __restrict__ x1, const float* __restrict__ g,
                const float* __restrict__ bb, bf16* __restrict__ out) {
  const int token = blockIdx.x * 4 + (threadIdx.x >> 6);  // < 32768
  const int lane = threadIdx.x & 63;
  const float* src = x1 + (size_t)token * 768;
  bf16* o = out + (size_t)token * 768;
  float vals[12], s = 0.f, ss = 0.f;
  #pragma unroll
  for (int t = 0; t < 12; ++t) {
    float v = src[lane + 64 * t];
    vals[t] = v; s += v; ss += v * v;
  }
  #pragma unroll
  for (int d = 32; d > 0; d >>= 1) { s += __shfl_xor(s, d); ss += __shfl_xor(ss, d); }
  const float mu = s * (1.f / 768.f);
  const float var = ss * (1.f / 768.f) - mu * mu;
  const float inv = rsqrtf(var + 1e-6f);
  #pragma unroll
  for (int t = 0; t < 12; ++t) {
    const int c = lane + 64 * t;
    o[c] = __float2bfloat16((vals[t] - mu) * inv * g[c] + bb[c]);
  }
}

// ---------------- generic bf16 GEMM, 128x128 tile, BK=32, 2-phase dbuf ------
// EPI 0: qkv -> q/k/v bufs in [head][MPAD][64] layout (LDS-staged stores)
// EPI 1: proj (A in [head][MPAD][64]) + unpartition + residual (f32)
// EPI 2: gelu -> bf16 [M][3072] (LDS-staged stores)
// EPI 3: dense residual add (f32)
// K % 64 == 0 required (768 / 3072).
template<int EPI>
__global__ __launch_bounds__(256)
void gemm_bf16(const bf16* __restrict__ A, const bf16* __restrict__ Bt,
               const float* __restrict__ bias, int K, int Mreal,
               const float* __restrict__ fin, float* __restrict__ fout,
               bf16* __restrict__ ob0, bf16* __restrict__ ob1, bf16* __restrict__ ob2) {
  __shared__ __align__(16) bf16 SMEM[16384];                 // 32 KB
  bf16* const lA[2] = { SMEM, SMEM + 4096 };
  bf16* const lB[2] = { SMEM + 8192, SMEM + 12288 };
  const int tid = threadIdx.x;
  const int lane = tid & 63, wv = tid >> 6;
  const int lr = lane & 15, hi = lane >> 4;
  const int wm = wv >> 1, wn = wv & 1;

  // bijective chunked XCD swizzle (m204): same-A blocks land on one XCD
  const int gx = gridDim.x;
  const int nwg = gx * gridDim.y;
  int lin = blockIdx.y * gx + blockIdx.x;
  {
    const int q8 = nwg >> 3, r8 = nwg & 7;
    const int xcd = lin & 7, pos = lin >> 3;
    lin = (xcd < r8 ? xcd * (q8 + 1) : r8 * (q8 + 1) + (xcd - r8) * q8) + pos;
  }
  const size_t arow0 = (size_t)(lin / gx) * 128;
  const size_t brow0 = (size_t)(lin % gx) * 128;
  f32x4 acc[4][4] = {};

  auto stage = [&](bf16* bufA, bf16* bufB, int kt) {
    const int k0 = kt * 32;
    #pragma unroll
    for (int it = 0; it < 2; ++it) {
      const int seg = it * 256 + tid;
      const int row = seg >> 2, kq = seg & 3;
      const size_t dst = (size_t)(it * 256 + wv * 64) * 8;
      if constexpr (EPI == 1) {
        const int k = k0 + kq * 8;   // A layout: [head][MPAD][64]
        gload_lds16(A + ((size_t)(k >> 6) * MPAD + arow0 + row) * 64 + (k & 63), bufA + dst);
      } else {
        gload_lds16(A + (arow0 + row) * K + k0 + kq * 8, bufA + dst);
      }
      gload_lds16(Bt + (brow0 + row) * K + k0 + kq * 8, bufB + dst);
    }
  };
  auto compute = [&](const bf16* bufA, const bf16* bufB) {
    short8 af[4], bfr[4];
    #pragma unroll
    for (int m = 0; m < 4; ++m) af[m] = *(const short8*)&bufA[(wm * 64 + m * 16 + lr) * 32 + hi * 8];
    #pragma unroll
    for (int n = 0; n < 4; ++n) bfr[n] = *(const short8*)&bufB[(wn * 64 + n * 16 + lr) * 32 + hi * 8];
    #pragma unroll
    for (int m = 0; m < 4; ++m)
      #pragma unroll
      for (int n = 0; n < 4; ++n)
        acc[m][n] = mfma16x16x32(af[m], bfr[n], acc[m][n]);
  };

  const int nt = K >> 5;               // even
  stage(lA[0], lB[0], 0);
  __syncthreads();                     // drains vmcnt(0): tile 0 staged
  for (int t = 0; t < nt; t += 2) {
    if (t + 1 < nt) stage(lA[1], lB[1], t + 1);
    compute(lA[0], lB[0]);
    __syncthreads();
    if (t + 2 < nt) stage(lA[0], lB[0], t + 2);
    compute(lA[1], lB[1]);
    __syncthreads();
  }

  if constexpr (EPI == 0 || EPI == 2) {
    // ---- LDS-staged coalesced bf16 epilogue ----
    bf16* ct = SMEM;                   // 128x128 bf16 tile, XOR-swizzled rows
    #pragma unroll
    for (int n = 0; n < 4; ++n) {
      const int col = wn * 64 + n * 16 + lr;         // tile-local
      const float bv = bias[(int)brow0 + col];
      #pragma unroll
      for (int m = 0; m < 4; ++m) {
        #pragma unroll
        for (int e = 0; e < 4; ++e) {
          const int row = wm * 64 + m * 16 + hi * 4 + e;
          float v = acc[m][n][e] + bv;
          if constexpr (EPI == 2) v = 0.5f * v * (1.f + erff(v * 0.70710678118f));
          const int byte = (row << 8) + (col << 1);
          *(bf16*)((char*)ct + (byte ^ ((row & 7) << 5))) = __float2bfloat16(v);
        }
      }
    }
    __syncthreads();
    #pragma unroll
    for (int i = 0; i < 8; ++i) {
      const int lin16 = i * 256 + tid;           // 16-B unit index
      const int row = lin16 >> 4;
      const int u   = lin16 & 15;
      const int byte = (row << 8) + (u << 4);
      const short8 val = *(const short8*)((char*)ct + (byte ^ ((row & 7) << 5)));
      const int grow = (int)arow0 + row;
      const int gcol = (int)brow0 + u * 8;
      if constexpr (EPI == 0) {
        if (grow < Mreal) {
          const int which = gcol / 768, head = (gcol >> 6) % 12, d = gcol & 63;
          bf16* dstb = (which == 0) ? ob0 : ((which == 1) ? ob1 : ob2);
          *(short8*)&dstb[((size_t)head * MPAD + grow) * 64 + d] = val;
        }
      } else {
        *(short8*)&ob0[(size_t)grow * 3072 + gcol] = val;
      }
    }
  } else {
    // ---- f32 residual epilogues (direct) ----
    #pragma unroll
    for (int n = 0; n < 4; ++n) {
      const int col = (int)brow0 + wn * 64 + n * 16 + lr;
      const float bv = bias[col];
      #pragma unroll
      for (int m = 0; m < 4; ++m) {
        #pragma unroll
        for (int e = 0; e < 4; ++e) {
          const int row = (int)arow0 + wm * 64 + m * 16 + hi * 4 + e;
          const float v = acc[m][n][e] + bv;
          if constexpr (EPI == 1) {
            if (row < Mreal) {
              const int win = row / 196, tok = row % 196;
              const int b_ = win / 25, wh = (win / 5) % 5, ww = win % 5;
              const int i = tok / 14, j = tok % 14;
              const int h = wh * 14 + i, w = ww * 14 + j;
              if (h < 64 && w < 64) {
                const size_t idx = ((size_t)((b_ * 64 + h) * 64 + w)) * 768 + col;
                fout[idx] = fin[idx] + v;
              }
            }
          } else {
            const size_t idx = (size_t)row * 768 + col;
            fout[idx] = fin[idx] + v;
          }
        }
      }
    }
  }
}

// ---------------- fused window attention, one block per (window, head) -------
// q/k/v/aout all in [head][MPAD][64] layout; window rows at win*196.
// Swapped-operand design: S^T = mfma(K, Q) so each lane owns one q-row (q = lr).
// P stays in registers (cvt_pk + 2-round shfl exchange), PV computed as O^T.
__global__ __launch_bounds__(256)
void attn_kernel(const bf16* __restrict__ qb, const bf16* __restrict__ kb,
                 const bf16* __restrict__ vb, const float* __restrict__ rph,
                 const float* __restrict__ rpw, bf16* __restrict__ aout) {
  __shared__ __align__(16) char SM[65248];
  bf16* pbh    = (bf16*)SM;
  bf16* pbw    = (bf16*)(SM + 4096);
  bf16* Gh     = (bf16*)(SM + 8192);
  bf16* Gw     = (bf16*)(SM + 23168);
  char* klds   = SM;                    // [200 rows][128 B], XOR-swizzled
  char* vtb    = SM + 25600;            // [64 d][448 B], XOR-swizzled
  bf16* relh_s = (bf16*)(SM + 54272);   // [196][14]
  bf16* relw_s = (bf16*)(SM + 59760);   // [196][14]

  const int bh = blockIdx.x;             // 0..2399
  const int win = bh / 12, head = bh % 12;
  const size_t base = ((size_t)head * MPAD + win * 196) * 64;
  const bf16* Q  = qb + base;
  const bf16* Kp = kb + base;
  const bf16* Vp = vb + base;
  const int tid = threadIdx.x, lane = tid & 63, wv = tid >> 6;
  const int lr = lane & 15, hi = lane >> 4;

  // ---- phase A0: stage rel_pos tables (bf16, zero-padded to 32 rows) ----
  for (int i = tid; i < 32 * 64; i += 256) {
    const int r = i >> 6, c = i & 63;
    const bool ok = r < 27;
    pbh[i] = __float2bfloat16(ok ? rph[r * 64 + c] : 0.f);
    pbw[i] = __float2bfloat16(ok ? rpw[r * 64 + c] : 0.f);
  }
  __syncthreads();
  // ---- phase A: G = Q @ relpos^T via MFMA ----
  {
    short8 bh00 = *(const short8*)&pbh[(lr) * 64 + hi * 8];
    short8 bh01 = *(const short8*)&pbh[(lr) * 64 + 32 + hi * 8];
    short8 bh10 = *(const short8*)&pbh[(16 + lr) * 64 + hi * 8];
    short8 bh11 = *(const short8*)&pbh[(16 + lr) * 64 + 32 + hi * 8];
    short8 bw00 = *(const short8*)&pbw[(lr) * 64 + hi * 8];
    short8 bw01 = *(const short8*)&pbw[(lr) * 64 + 32 + hi * 8];
    short8 bw10 = *(const short8*)&pbw[(16 + lr) * 64 + hi * 8];
    short8 bw11 = *(const short8*)&pbw[(16 + lr) * 64 + 32 + hi * 8];
    for (int mt = wv; mt < 13; mt += 4) {
      const short8 a0 = *(const short8*)&Q[(mt * 16 + lr) * 64 + hi * 8];
      const short8 a1 = *(const short8*)&Q[(mt * 16 + lr) * 64 + 32 + hi * 8];
      f32x4 g0 = {}, g1 = {}, g2 = {}, g3 = {};
      g0 = mfma16x16x32(a0, bh00, g0); g0 = mfma16x16x32(a1, bh01, g0);
      g1 = mfma16x16x32(a0, bh10, g1); g1 = mfma16x16x32(a1, bh11, g1);
      g2 = mfma16x16x32(a0, bw00, g2); g2 = mfma16x16x32(a1, bw01, g2);
      g3 = mfma16x16x32(a0, bw10, g3); g3 = mfma16x16x32(a1, bw11, g3);
      #pragma unroll
      for (int e = 0; e < 4; ++e) {
        const int row = mt * 16 + hi * 4 + e;
        Gh[row * 36 + lr]      = __float2bfloat16(g0[e]);
        Gh[row * 36 + 16 + lr] = __float2bfloat16(g1[e]);
        Gw[row * 36 + lr]      = __float2bfloat16(g2[e]);
        Gw[row * 36 + 16 + lr] = __float2bfloat16(g3[e]);
      }
    }
  }
  __syncthreads();
  // ---- phase B: gather G -> regs ----
  bf16 ghr[11], gwr[11];
  #pragma unroll
  for (int t = 0; t < 11; ++t) {
    const int i = tid + t * 256;
    if (i < 196 * 14) {
      const int q = i / 14, kk = i - (i / 14) * 14;
      const int rh = q / 14 - kk + 13;
      const int rw2 = q - (q / 14) * 14 - kk + 13;
      ghr[t] = Gh[q * 36 + rh];
      gwr[t] = Gw[q * 36 + rw2];
    }
  }
  __syncthreads();
  // ---- phase C: write rel tables; stage K (swizzled gload_lds); stage V^T ----
  #pragma unroll
  for (int t = 0; t < 11; ++t) {
    const int i = tid + t * 256;
    if (i < 196 * 14) { relh_s[i] = ghr[t]; relw_s[i] = gwr[t]; }
  }
  for (int c = wv; c < 25; c += 4) {          // 25 calls x 1024 B = 200 K-rows
    const int row = c * 8 + (lane >> 3);
    const int ch  = (lane & 7) ^ (row & 7);   // pre-swizzled global source
    gload_lds16(Kp + row * 64 + ch * 8, klds + c * 1024);
  }
  for (int i = tid; i < 196 * 8; i += 256) {  // V^T staging (vectorized read)
    const int key = i >> 3, dg = (i & 7) * 8;
    const short8 v = *(const short8*)&Vp[key * 64 + dg];
    #pragma unroll
    for (int j = 0; j < 8; ++j) {
      const int idx = (dg + j) * 448 + key * 2;
      *(bf16*)(vtb + (idx ^ (j << 4))) = ((const bf16*)&v)[j];
    }
  }
  for (int i = tid; i < 64 * 28; i += 256) {  // zero-pad keys 196..223
    const int d = i / 28, key = 196 + i - (i / 28) * 28;
    const int idx = d * 448 + key * 2;
    *(bf16*)(vtb + (idx ^ ((d & 7) << 4))) = __float2bfloat16(0.f);
  }
  __syncthreads();

  // ---- main loop over q-tiles ----
  for (int qt = wv; qt < 13; qt += 4) {
    const int q = qt * 16 + lr;               // this lane's q-row
    const int qc = q < 196 ? q : 195;
    const short8 bq0 = *(const short8*)&Q[(qt * 16 + lr) * 64 + hi * 8];
    const short8 bq1 = *(const short8*)&Q[(qt * 16 + lr) * 64 + 32 + hi * 8];
    // S^T = K . Q^T  (13 key tiles of 16)
    f32x4 s[13];
    __builtin_amdgcn_s_setprio(1);
    #pragma unroll
    for (int nt = 0; nt < 13; ++nt) {
      const int key = nt * 16 + lr;
      const char* kr = klds + key * 128;
      const short8 ka0 = *(const short8*)(kr + (((hi) ^ (key & 7)) << 4));
      const short8 ka1 = *(const short8*)(kr + (((hi + 4) ^ (key & 7)) << 4));
      f32x4 z = {};
      z = mfma16x16x32(ka0, bq0, z);
      z = mfma16x16x32(ka1, bq1, z);
      s[nt] = z;      // s[nt][e] = S[q=lr][key = nt*16 + hi*4 + e]
    }
    __builtin_amdgcn_s_setprio(0);
    // bias + mask + softmax (per-lane row; cross-lane over {lr,lr+16,lr+32,lr+48})
    float mx = -3.0e38f;
    #pragma unroll
    for (int nt = 0; nt < 13; ++nt) {
      #pragma unroll
      for (int e = 0; e < 4; ++e) {
        const int key = nt * 16 + hi * 4 + e;
        const int kh = key / 14, kw = key - kh * 14;
        float v = s[nt][e] * 0.125f + __bfloat162float(relh_s[qc * 14 + kh])
                                    + __bfloat162float(relw_s[qc * 14 + kw]);
        v = (key < 196) ? v : -3.0e38f;
        s[nt][e] = v;
        mx = fmaxf(mx, v);
      }
    }
    mx = fmaxf(mx, __shfl_xor(mx, 16));
    mx = fmaxf(mx, __shfl_xor(mx, 32));
    float sm = 0.f;
    #pragma unroll
    for (int nt = 0; nt < 13; ++nt)
      #pragma unroll
      for (int e = 0; e < 4; ++e) {
        const float p = __expf(s[nt][e] - mx);
        s[nt][e] = p; sm += p;
      }
    sm += __shfl_xor(sm, 16);
    sm += __shfl_xor(sm, 32);
    const float rinv = 1.f / sm;
    // O^T = V^T . P^T  (7 key chunks of 32); P frag built in-register
    f32x4 o[4] = {};
    #pragma unroll
    for (int kk = 0; kk < 7; ++kk) {
      const uint32_t x0 = cvtpk(s[2 * kk][0] * rinv, s[2 * kk][1] * rinv);
      const uint32_t x1 = cvtpk(s[2 * kk][2] * rinv, s[2 * kk][3] * rinv);
      const uint32_t y0 = cvtpk(s[2 * kk + 1][0] * rinv, s[2 * kk + 1][1] * rinv);
      const uint32_t y1 = cvtpk(s[2 * kk + 1][2] * rinv, s[2 * kk + 1][3] * rinv);
      // round 1: xor 32 (hi-group g <-> g^2), send y for g<2 else x
      const uint32_t s0 = (hi < 2) ? y0 : x0, s1 = (hi < 2) ? y1 : x1;
      const uint32_t t0 = __shfl_xor(s0, 32), t1 = __shfl_xor(s1, 32);
      // round 2: xor 16; g∈{1,2} send own, g∈{0,3} send t
      const uint32_t o0 = (hi < 2) ? x0 : y0, o1 = (hi < 2) ? x1 : y1;
      const bool sendOwn = (hi == 1) || (hi == 2);
      const uint32_t u0 = sendOwn ? o0 : t0, u1 = sendOwn ? o1 : t1;
      const uint32_t r0 = __shfl_xor(u0, 16), r1 = __shfl_xor(u1, 16);
      // assemble frag: [first(2dw), second(2dw)]
      union { uint32_t u[4]; short8 v; } pf;
      pf.u[0] = (hi == 0) ? x0 : ((hi == 2) ? t0 : r0);
      pf.u[1] = (hi == 0) ? x1 : ((hi == 2) ? t1 : r1);
      pf.u[2] = (hi == 3) ? y0 : ((hi == 1) ? t0 : r0);
      pf.u[3] = (hi == 3) ? y1 : ((hi == 1) ? t1 : r1);
      __builtin_amdgcn_s_setprio(1);
      #pragma unroll
      for (int n2 = 0; n2 < 4; ++n2) {
        const int d = n2 * 16 + lr;
        const int idx = d * 448 + (kk * 32 + hi * 8) * 2;
        const short8 va = *(const short8*)(vtb + (idx ^ ((lr & 7) << 4)));
        o[n2] = mfma16x16x32(va, pf.v, o[n2]);   // o[n2][e] = O[q][d=n2*16+hi*4+e]
      }
      __builtin_amdgcn_s_setprio(0);
    }
    // store O rows (dense 8B per lane, aout[head][MPAD][64])
    if (q < 196) {
      bf16* orow = aout + ((size_t)head * MPAD + win * 196 + q) * 64;
      #pragma unroll
      for (int n2 = 0; n2 < 4; ++n2) {
        uint32_t d0 = cvtpk(o[n2][0], o[n2][1]);
        uint32_t d1 = cvtpk(o[n2][2], o[n2][3]);
        uint32_t* dst = (uint32_t*)&orow[n2 * 16 + hi * 4];
        dst[0] = d0; dst[1] = d1;
      }
    }
  }
}

// ---------------- host ----------------
extern "C" void kernel_launch(void* const* d_in, const int* in_sizes, int n_in,
                              void* d_out, int out_size, void* d_ws, size_t ws_size,
                              hipStream_t stream) {
  (void)in_sizes; (void)n_in; (void)out_size; (void)ws_size;
  const float* x      = (const float*)d_in[0];
  const float* ln1_g  = (const float*)d_in[1];
  const float* ln1_b  = (const float*)d_in[2];
  const float* qkv_w  = (const float*)d_in[3];
  const float* qkv_b  = (const float*)d_in[4];
  const float* proj_w = (const float*)d_in[5];
  const float* proj_b = (const float*)d_in[6];
  const float* rph    = (const float*)d_in[7];
  const float* rpw    = (const float*)d_in[8];
  const float* ln2_g  = (const float*)d_in[9];
  const float* ln2_b  = (const float*)d_in[10];
  const float* w1     = (const float*)d_in[11];
  const float* b1v    = (const float*)d_in[12];
  const float* w2     = (const float*)d_in[13];
  const float* b2v    = (const float*)d_in[14];
  float* outp = (float*)d_out;   // also serves as x1 (written by proj epilogue)

  // -------- workspace layout with liveness-based aliasing --------
  char* ws = (char*)d_ws;
  size_t off = 0;
  auto alloc = [&](size_t bytes) { char* p = ws + off; off += (bytes + 255) & ~(size_t)255; return p; };
  bf16* qkv_wt  = (bf16*)alloc((size_t)2304 * 768 * 2);
  bf16* proj_wt = (bf16*)alloc((size_t)768 * 768 * 2);
  bf16* w1t     = (bf16*)alloc((size_t)3072 * 768 * 2);
  bf16* w2t     = (bf16*)alloc((size_t)768 * 3072 * 2);
  // region B: xnwin (qkv phase) -> attnout [12][MPAD][64] (proj) -> xn2 (mlp)
  const size_t szB1 = (size_t)MPAD * 768 * 2;
  const size_t szB2 = (size_t)TOK2 * 768 * 2;
  char* regB = alloc(szB1 > szB2 ? szB1 : szB2);
  // region C: q/k/v [12][MPAD][64] each (attn phase) -> hbuf (mlp phase)
  const size_t szQKV = (size_t)3 * 12 * MPAD * 64 * 2;
  const size_t szH   = (size_t)TOK2 * 3072 * 2;
  char* regC = alloc(szQKV > szH ? szQKV : szH);

  bf16* xnwin   = (bf16*)regB;
  bf16* attnout = (bf16*)regB;
  bf16* xn2     = (bf16*)regB;
  bf16* qbuf    = (bf16*)regC;
  bf16* kbuf    = qbuf + (size_t)12 * MPAD * 64;
  bf16* vbuf    = kbuf + (size_t)12 * MPAD * 64;
  bf16* hbuf    = (bf16*)regC;

  // weights -> bf16 transposed [N][K]
  transpose_cast<<<dim3(2304 / 32, 768 / 32), 256, 0, stream>>>(qkv_w, qkv_wt, 768, 2304);
  transpose_cast<<<dim3(768 / 32, 768 / 32), 256, 0, stream>>>(proj_w, proj_wt, 768, 768);
  transpose_cast<<<dim3(3072 / 32, 768 / 32), 256, 0, stream>>>(w1, w1t, 768, 3072);
  transpose_cast<<<dim3(768 / 32, 3072 / 32), 256, 0, stream>>>(w2, w2t, 3072, 768);

  // LN1 + window partition
  ln1_partition<<<dim3(MROWS / 4), 256, 0, stream>>>(x, ln1_g, ln1_b, xnwin);

  // qkv GEMM [39296 x 2304] = xnwin @ qkv_w -> q/k/v [head][MPAD][64]
  gemm_bf16<0><<<dim3(2304 / 128, MPAD / 128), 256, 0, stream>>>(
      xnwin, qkv_wt, qkv_b, 768, MROWS, nullptr, nullptr, qbuf, kbuf, vbuf);

  // attention (writes attnout = regB; xnwin dead now)
  attn_kernel<<<dim3(2400), 256, 0, stream>>>(qbuf, kbuf, vbuf, rph, rpw, attnout);

  // proj GEMM + unpartition + residual -> x1 (= outp, f32)
  gemm_bf16<1><<<dim3(768 / 128, MPAD / 128), 256, 0, stream>>>(
      attnout, proj_wt, proj_b, 768, MROWS, x, outp, nullptr, nullptr, nullptr);

  // LN2 (writes xn2, aliases attnout -- dead now)
  ln2_kernel<<<dim3(TOK2 / 4), 256, 0, stream>>>(outp, ln2_g, ln2_b, xn2);

  // MLP (hbuf aliases q/k/v -- dead now)
  gemm_bf16<2><<<dim3(3072 / 128, TOK2 / 128), 256, 0, stream>>>(
      xn2, w1t, b1v, 768, TOK2, nullptr, nullptr, hbuf, nullptr, nullptr);
  gemm_bf16<3><<<dim3(768 / 128, TOK2 / 128), 256, 0, stream>>>(
      hbuf, w2t, b2v, 3072, TOK2, outp, outp, nullptr, nullptr, nullptr);
}